// Round 12
// baseline (506.698 us; speedup 1.0000x reference)
//
#include <hip/hip_runtime.h>
#include <math.h>

#define NN   50000
#define NE   500000
#define NTT  10000
#define ETT  100000
#define HF   320      // h_final row = 128 + 3*64
#define EFW  160      // e_final row = 64 + 3*32
#define NT3  7813     // ceil(NE/64)
#define GRID3 1024

typedef __attribute__((ext_vector_type(8))) short short8_t;
typedef __attribute__((ext_vector_type(4))) float f32x4;

__device__ __forceinline__ float silu_f(float x) { return x / (1.f + __expf(-x)); }

__device__ __forceinline__ short f2bf(float f) {
    unsigned u = __float_as_uint(f);
    unsigned r = (u + 0x7fffu + ((u >> 16) & 1u)) >> 16;
    return (short)r;
}
__device__ __forceinline__ float bf2f(short s) {
    return __uint_as_float(((unsigned)(unsigned short)s) << 16);
}
// XOR swizzle helpers: return SHORT index. stride 256 shorts (512B) / 128 shorts (256B)
__device__ __forceinline__ int swz256(int row, int col) {
    return row * 256 + (((col << 1) ^ ((row & 7) << 4)) >> 1);
}
__device__ __forceinline__ int swz128(int row, int col) {
    return row * 128 + (((col << 1) ^ ((row & 7) << 4)) >> 1);
}

// ---------------- K0: fold W_nsp into W_left/W_right AND W_nsp@W_at1 ----------------
__global__ __launch_bounds__(256) void k0_all(
    const float* __restrict__ W_nsp, const float* __restrict__ b_nsp,
    const float* __restrict__ W_left, const float* __restrict__ b_left,
    const float* __restrict__ W_right, const float* __restrict__ b_right,
    const float* __restrict__ W_at1, const float* __restrict__ b_at1,
    float* __restrict__ Wl, float* __restrict__ bl,
    float* __restrict__ Wr, float* __restrict__ br,
    float* __restrict__ Wc1, float* __restrict__ bc1)
{
    if (blockIdx.x < 64) {
        int idx = blockIdx.x * 256 + threadIdx.x;
        int i = idx >> 7, j = idx & 127;
        float al = 0.f, ar = 0.f;
        for (int k = 0; k < 128; ++k) {
            float w = W_nsp[i * 128 + k];
            al = fmaf(w, W_left[k * 128 + j], al);
            ar = fmaf(w, W_right[k * 128 + j], ar);
        }
        Wl[idx] = al; Wr[idx] = ar;
        if (i == 0) {
            float cl = 0.f, cr = 0.f;
            for (int k = 0; k < 128; ++k) {
                float bn = b_nsp[k];
                cl = fmaf(bn, W_left[k * 128 + j], cl);
                cr = fmaf(bn, W_right[k * 128 + j], cr);
            }
            bl[j] = cl + b_left[j];
            br[j] = cr + b_right[j];
        }
    } else {
        int idx = (blockIdx.x - 64) * 256 + threadIdx.x;
        int i = idx >> 7, j = idx & 127;
        float a = 0.f;
        for (int k = 0; k < 128; ++k)
            a = fmaf(W_nsp[i * 128 + k], W_at1[k * 128 + j], a);
        Wc1[idx] = a;
        if (i == 0) {
            float c = 0.f;
            for (int k = 0; k < 128; ++k)
                c = fmaf(b_nsp[k], W_at1[k * 128 + j], c);
            bc1[j] = c + b_at1[j];
        }
    }
}

// ---------------- K1: hl/hr via MFMA, bf16 outputs ----------------
#define KP1 136
__global__ __launch_bounds__(256) void k1_mfma(
    const float* __restrict__ h_final,
    const float* __restrict__ Wl, const float* __restrict__ bl,
    const float* __restrict__ Wr, const float* __restrict__ br,
    short* __restrict__ hlb, short* __restrict__ hrb)
{
    __shared__ __align__(16) short sx[64][KP1];
    const int tid = threadIdx.x;
    const int w = tid >> 6, lane = tid & 63, g = lane >> 4, ln = lane & 15;

    short8_t bfr[4][4];
    float bias[4];
    #pragma unroll
    for (int nf = 0; nf < 4; ++nf) {
        int col = w * 64 + nf * 16 + ln;
        const float* Wsrc = (col < 128) ? Wl : Wr;
        int cc = col & 127;
        bias[nf] = (col < 128) ? bl[cc] : br[cc];
        #pragma unroll
        for (int k0 = 0; k0 < 4; ++k0) {
            short8_t bb;
            #pragma unroll
            for (int j = 0; j < 8; ++j)
                bb[j] = f2bf(Wsrc[(k0 * 32 + g * 8 + j) * 128 + cc]);
            bfr[k0][nf] = bb;
        }
    }

    const int base = blockIdx.x * 64;
    {
        const int e = tid >> 2, q = tid & 3;
        const int n = base + e;
        #pragma unroll
        for (int i = 0; i < 8; ++i) {
            float4 v = make_float4(0.f, 0.f, 0.f, 0.f);
            if (n < NN) v = *(const float4*)&h_final[(size_t)n * HF + q * 32 + i * 4];
            short4 s4; s4.x = f2bf(v.x); s4.y = f2bf(v.y); s4.z = f2bf(v.z); s4.w = f2bf(v.w);
            *(short4*)&sx[e][q * 32 + i * 4] = s4;
        }
    }
    __syncthreads();
    f32x4 acc[4][4];
    #pragma unroll
    for (int mf = 0; mf < 4; ++mf)
        #pragma unroll
        for (int nf = 0; nf < 4; ++nf)
            acc[mf][nf] = (f32x4){0.f, 0.f, 0.f, 0.f};
    #pragma unroll
    for (int k0 = 0; k0 < 4; ++k0) {
        short8_t a[4];
        #pragma unroll
        for (int mf = 0; mf < 4; ++mf)
            a[mf] = *(const short8_t*)&sx[mf * 16 + ln][k0 * 32 + g * 8];
        #pragma unroll
        for (int mf = 0; mf < 4; ++mf)
            #pragma unroll
            for (int nf = 0; nf < 4; ++nf)
                acc[mf][nf] = __builtin_amdgcn_mfma_f32_16x16x32_bf16(
                    a[mf], bfr[k0][nf], acc[mf][nf], 0, 0, 0);
    }
    #pragma unroll
    for (int mf = 0; mf < 4; ++mf)
        #pragma unroll
        for (int nf = 0; nf < 4; ++nf) {
            int col = w * 64 + nf * 16 + ln;
            #pragma unroll
            for (int r = 0; r < 4; ++r) {
                int n = base + mf * 16 + g * 4 + r;
                if (n < NN) {
                    short v = f2bf(acc[mf][nf][r] + bias[nf]);
                    if (col < 128) hlb[(size_t)n * 128 + col] = v;
                    else           hrb[(size_t)n * 128 + col - 128] = v;
                }
            }
        }
}

// ---------------- K2: atom head via folded MFMA (x@Wc1 -> silu -> @W_at2) ----------------
__global__ __launch_bounds__(256) void k2_mfma(
    const float* __restrict__ h_final, const int* __restrict__ tn,
    const float* __restrict__ Wc1, const float* __restrict__ bc1,
    const float* __restrict__ W_at2, const float* __restrict__ b_at2,
    float* __restrict__ out)
{
    __shared__ __align__(16) short sxf[64 * 128];
    __shared__ __align__(16) short syf[64 * 128];
    const int tid = threadIdx.x;
    const int w = tid >> 6, lane = tid & 63, g = lane >> 4, ln = lane & 15;

    short8_t bfr1[4][2];
    float biasc[2];
    #pragma unroll
    for (int nf = 0; nf < 2; ++nf) {
        int col = w * 32 + nf * 16 + ln;
        biasc[nf] = bc1[col];
        #pragma unroll
        for (int k0 = 0; k0 < 4; ++k0) {
            short8_t bb;
            #pragma unroll
            for (int j = 0; j < 8; ++j)
                bb[j] = f2bf(Wc1[(k0 * 32 + g * 8 + j) * 128 + col]);
            bfr1[k0][nf] = bb;
        }
    }
    short8_t bfr2[4][2];
    float ba2v[2];
    #pragma unroll
    for (int nf = 0; nf < 2; ++nf) {
        ba2v[nf] = b_at2[nf * 16 + ln];
        #pragma unroll
        for (int k0 = 0; k0 < 4; ++k0) {
            short8_t bb;
            #pragma unroll
            for (int j = 0; j < 8; ++j)
                bb[j] = f2bf(W_at2[(k0 * 32 + g * 8 + j) * 32 + nf * 16 + ln]);
            bfr2[k0][nf] = bb;
        }
    }

    const int base = blockIdx.x * 64;
    {
        const int e = tid >> 2, q = tid & 3;
        const int t = base + e;
        const bool valid = (t < NTT);
        const int node = valid ? tn[t] : 0;
        #pragma unroll
        for (int i = 0; i < 8; ++i) {
            float4 v = make_float4(0.f, 0.f, 0.f, 0.f);
            if (valid) v = *(const float4*)&h_final[(size_t)node * HF + q * 32 + i * 4];
            short4 s4; s4.x = f2bf(v.x); s4.y = f2bf(v.y); s4.z = f2bf(v.z); s4.w = f2bf(v.w);
            *(short4*)&sxf[swz128(e, q * 32 + i * 4)] = s4;
        }
    }
    __syncthreads();
    f32x4 acc[4][2];
    #pragma unroll
    for (int mf = 0; mf < 4; ++mf)
        #pragma unroll
        for (int nf = 0; nf < 2; ++nf)
            acc[mf][nf] = (f32x4){0.f, 0.f, 0.f, 0.f};
    #pragma unroll
    for (int k0 = 0; k0 < 4; ++k0) {
        short8_t a[4];
        #pragma unroll
        for (int mf = 0; mf < 4; ++mf)
            a[mf] = *(const short8_t*)&sxf[swz128(mf * 16 + ln, k0 * 32 + g * 8)];
        #pragma unroll
        for (int mf = 0; mf < 4; ++mf)
            #pragma unroll
            for (int nf = 0; nf < 2; ++nf)
                acc[mf][nf] = __builtin_amdgcn_mfma_f32_16x16x32_bf16(
                    a[mf], bfr1[k0][nf], acc[mf][nf], 0, 0, 0);
    }
    #pragma unroll
    for (int mf = 0; mf < 4; ++mf)
        #pragma unroll
        for (int nf = 0; nf < 2; ++nf)
            #pragma unroll
            for (int r = 0; r < 4; ++r)
                syf[swz128(mf * 16 + g * 4 + r, w * 32 + nf * 16 + ln)] =
                    f2bf(silu_f(acc[mf][nf][r] + biasc[nf]));
    __syncthreads();
    f32x4 z[2];
    z[0] = (f32x4){0.f,0.f,0.f,0.f}; z[1] = (f32x4){0.f,0.f,0.f,0.f};
    #pragma unroll
    for (int k0 = 0; k0 < 4; ++k0) {
        short8_t a2 = *(const short8_t*)&syf[swz128(w * 16 + ln, k0 * 32 + g * 8)];
        #pragma unroll
        for (int nf = 0; nf < 2; ++nf)
            z[nf] = __builtin_amdgcn_mfma_f32_16x16x32_bf16(a2, bfr2[k0][nf], z[nf], 0, 0, 0);
    }
    #pragma unroll
    for (int nf = 0; nf < 2; ++nf)
        #pragma unroll
        for (int r = 0; r < 4; ++r) {
            int t = base + w * 16 + g * 4 + r;
            if (t < NTT) out[(size_t)t * 32 + nf * 16 + ln] = z[nf][r] + ba2v[nf];
        }
}

// ---------------- K3pre: per-edge vector norms -> bf16 Xn[NE][32] ----------------
__global__ __launch_bounds__(256) void k3pre(
    const float* __restrict__ e_final, short* __restrict__ Xn)
{
    const int tid = threadIdx.x;
    const int e = blockIdx.x * 32 + (tid >> 3);
    const int sub = tid & 7;
    const float* p = &e_final[(size_t)e * EFW + 64 + sub * 12];
    float4 a = *(const float4*)p;
    float4 b = *(const float4*)(p + 4);
    float4 c = *(const float4*)(p + 8);
    short4 o;
    o.x = f2bf(sqrtf(a.x*a.x + a.y*a.y + a.z*a.z));
    o.y = f2bf(sqrtf(a.w*a.w + b.x*b.x + b.y*b.y));
    o.z = f2bf(sqrtf(b.z*b.z + b.w*b.w + c.x*c.x));
    o.w = f2bf(sqrtf(c.y*c.y + c.z*c.z + c.w*c.w));
    *(short4*)&Xn[(size_t)e * 32 + sub * 4] = o;
}

// ---------------- K3: edge MLP, 8-wave blocks, split-butterfly epilogue ----------------
// Round 10 diagnosis: LN/dot butterflies = 1536 ds_swizzle/tile (~8.9k cyc on the
// shared LDS pipe) -- 3x the MFMA A-read cost; occupancy doesn't help a saturated
// pipe. Fix: value-splitting butterfly (exchange half the 16 values per stage):
// 15 shfl per reduction vs 64 -> 360 swizzles/tile. Final index mapping is static:
// lane ln ends with row (ln>>2)*16+g*4+(ln&3) -- identical sstat/spd layout.
__global__ __launch_bounds__(512, 4) void k3_edge(
    const float* __restrict__ e_final, const int* __restrict__ edge_index,
    const short* __restrict__ Xn,
    const short* __restrict__ hlb, const short* __restrict__ hrb,
    const float* __restrict__ r_t,
    const float* __restrict__ W_el1, const float* __restrict__ b_el1,
    const float* __restrict__ ln_g, const float* __restrict__ ln_b,
    const float* __restrict__ W_el2, const float* __restrict__ b_el2,
    float* __restrict__ delta)
{
    __shared__ __align__(16) short sxf[64 * 256];   // 32 KB, XOR-swizzled, K=224 used
    __shared__ float sstat[64][8][2];               // per-wave LN partials
    __shared__ float smu[64][2];
    __shared__ float spd[64][8];
    __shared__ float srel[64][4];
    __shared__ int   sidx[64];

    const int tid  = threadIdx.x;
    const int w    = tid >> 6;       // wave 0..7 -> cols [w*16, w*16+16)
    const int lane = tid & 63;
    const int g    = lane >> 4;
    const int ln   = lane & 15;
    const int es   = tid >> 3, qs = tid & 7;   // staging: 8 threads per edge

    // B fragments of W_el1 (224x128), one 16-col slice per wave
    short8_t bfr[7];
    #pragma unroll
    for (int k0 = 0; k0 < 7; ++k0) {
        short8_t bb;
        #pragma unroll
        for (int j = 0; j < 8; ++j)
            bb[j] = f2bf(W_el1[(k0 * 32 + g * 8 + j) * 128 + w * 16 + ln]);
        bfr[k0] = bb;
    }
    const float bias0 = b_el1[w * 16 + ln];
    const float gj0   = ln_g[w * 16 + ln];
    const float bj0   = ln_b[w * 16 + ln];
    const float w2j0  = W_el2[w * 16 + ln];
    const float b2 = b_el2[0];

    for (int t = blockIdx.x; t < NT3; t += GRID3) {
        __syncthreads();   // sxf & partial arrays free

        // ---- direct gather staging into swizzled sxf ----
        {
            const int ge = t * 64 + es;
            const bool valid = (ge < NE);
            int r = 0, c = 0;
            if (valid) { r = edge_index[ge]; c = edge_index[NE + ge]; }
            // e_scalar cols qs*8..+8
            #pragma unroll
            for (int i = 0; i < 2; ++i) {
                float4 v = make_float4(0.f, 0.f, 0.f, 0.f);
                if (valid) v = *(const float4*)&e_final[(size_t)ge * EFW + qs * 8 + i * 4];
                short4 s4; s4.x = f2bf(v.x); s4.y = f2bf(v.y);
                s4.z = f2bf(v.z); s4.w = f2bf(v.w);
                *(short4*)&sxf[swz256(es, qs * 8 + i * 4)] = s4;
            }
            // norms col 64+qs*4 (precomputed bf16)
            {
                short4 n0 = make_short4(0,0,0,0);
                if (valid) n0 = *(const short4*)&Xn[(size_t)ge * 32 + qs * 4];
                *(short4*)&sxf[swz256(es, 64 + qs * 4)] = n0;
            }
            // inter cols 96+qs*16..+16
            #pragma unroll
            for (int i = 0; i < 2; ++i) {
                short8_t hv, rv, pr;
                if (valid) {
                    hv = *(const short8_t*)&hlb[(size_t)r * 128 + qs * 16 + i * 8];
                    rv = *(const short8_t*)&hrb[(size_t)c * 128 + qs * 16 + i * 8];
                } else {
                    #pragma unroll
                    for (int jj = 0; jj < 8; ++jj) { hv[jj] = 0; rv[jj] = 0; }
                }
                #pragma unroll
                for (int jj = 0; jj < 8; ++jj)
                    pr[jj] = f2bf(bf2f(hv[jj]) * bf2f(rv[jj]));
                *(short8_t*)&sxf[swz256(es, 96 + qs * 16 + i * 8)] = pr;
            }
            if (qs == 0) {
                float rx = 0.f, ry = 0.f, rz = 0.f;
                if (valid) {
                    rx = r_t[r*3+0] - r_t[c*3+0];
                    ry = r_t[r*3+1] - r_t[c*3+1];
                    rz = r_t[r*3+2] - r_t[c*3+2];
                }
                sidx[es] = r;
                srel[es][0] = rx; srel[es][1] = ry; srel[es][2] = rz;
            }
        }
        __syncthreads();

        // ---- MFMA: y[64][16-slice] = x[64][224] @ W[:, w*16..+16) ----
        f32x4 acc[4];
        #pragma unroll
        for (int mf = 0; mf < 4; ++mf)
            acc[mf] = (f32x4){0.f, 0.f, 0.f, 0.f};
        #pragma unroll
        for (int k0 = 0; k0 < 7; ++k0) {
            short8_t a[4];
            #pragma unroll
            for (int mf = 0; mf < 4; ++mf)
                a[mf] = *(const short8_t*)&sxf[swz256(mf * 16 + ln, k0 * 32 + g * 8)];
            #pragma unroll
            for (int mf = 0; mf < 4; ++mf)
                acc[mf] = __builtin_amdgcn_mfma_f32_16x16x32_bf16(
                    a[mf], bfr[k0], acc[mf], 0, 0, 0);
        }

        // ---- LN stats via value-splitting butterfly (15 shfl per value-set) ----
        {
            float vs[16], vq[16];
            #pragma unroll
            for (int mf = 0; mf < 4; ++mf)
                #pragma unroll
                for (int r = 0; r < 4; ++r) {
                    float y0 = acc[mf][r] + bias0;
                    vs[mf * 4 + r] = y0;
                    vq[mf * 4 + r] = y0 * y0;
                }
            #pragma unroll
            for (int st = 0; st < 4; ++st) {
                const int m  = 8 >> st;      // 8,4,2,1
                const int Vh = 8 >> st;      // half the live count: 8,4,2,1
                const bool hib = (ln & m) != 0;
                #pragma unroll
                for (int i = 0; i < Vh; ++i) {
                    float ks = hib ? vs[i + Vh] : vs[i];
                    float ss = hib ? vs[i] : vs[i + Vh];
                    vs[i] = ks + __shfl_xor(ss, m);
                    float kq = hib ? vq[i + Vh] : vq[i];
                    float sq = hib ? vq[i] : vq[i + Vh];
                    vq[i] = kq + __shfl_xor(sq, m);
                }
            }
            int row = (ln >> 2) * 16 + g * 4 + (ln & 3);
            *(float2*)&sstat[row][w][0] = make_float2(vs[0], vq[0]);
        }
        __syncthreads();
        if (tid < 64) {
            float S = 0.f, Q = 0.f;
            #pragma unroll
            for (int i = 0; i < 4; ++i) {
                float4 s4 = *(const float4*)&sstat[tid][i * 2][0];
                S += s4.x + s4.z;
                Q += s4.y + s4.w;
            }
            float mu = S * (1.f / 128.f);
            float iv = rsqrtf(Q * (1.f / 128.f) - mu * mu + 1e-5f);
            *(float2*)&smu[tid][0] = make_float2(mu, iv);
        }
        __syncthreads();

        // ---- silu dot partials via the same split butterfly ----
        {
            float vd[16];
            #pragma unroll
            for (int mf = 0; mf < 4; ++mf)
                #pragma unroll
                for (int r = 0; r < 4; ++r) {
                    float2 mi = *(const float2*)&smu[mf * 16 + g * 4 + r][0];
                    float y0 = acc[mf][r] + bias0;
                    vd[mf * 4 + r] = silu_f((y0 - mi.x) * mi.y * gj0 + bj0) * w2j0;
                }
            #pragma unroll
            for (int st = 0; st < 4; ++st) {
                const int m  = 8 >> st;
                const int Vh = 8 >> st;
                const bool hib = (ln & m) != 0;
                #pragma unroll
                for (int i = 0; i < Vh; ++i) {
                    float kd = hib ? vd[i + Vh] : vd[i];
                    float sd = hib ? vd[i] : vd[i + Vh];
                    vd[i] = kd + __shfl_xor(sd, m);
                }
            }
            int row = (ln >> 2) * 16 + g * 4 + (ln & 3);
            spd[row][w] = vd[0];
        }
        __syncthreads();
        if (tid < 64) {
            int ge = t * 64 + tid;
            if (ge < NE) {
                float4 p4a = *(const float4*)&spd[tid][0];
                float4 p4b = *(const float4*)&spd[tid][4];
                float we = p4a.x + p4a.y + p4a.z + p4a.w
                         + p4b.x + p4b.y + p4b.z + p4b.w + b2;
                float rx = srel[tid][0], ry = srel[tid][1], rz = srel[tid][2];
                float d = sqrtf(rx*rx + ry*ry + rz*rz) + 1e-8f;
                float f = we / (d * (d + 1.f));
                int rr = sidx[tid];
                atomicAdd(&delta[rr*3+0], f*rx);
                atomicAdd(&delta[rr*3+1], f*ry);
                atomicAdd(&delta[rr*3+2], f*rz);
            }
        }
    }
}

// ---------------- K4a: G = H_s @ w_tp0 (bf16 out) ----------------
__global__ __launch_bounds__(256) void k4a_g(
    const float* __restrict__ h_final, const float* __restrict__ w_tp0,
    short* __restrict__ Gb)
{
    __shared__ __align__(16) short sx[64][KP1];
    const int tid = threadIdx.x;
    const int w = tid >> 6, lane = tid & 63, g = lane >> 4, ln = lane & 15;

    short8_t bfr[4][2];
    #pragma unroll
    for (int k0 = 0; k0 < 4; ++k0)
        #pragma unroll
        for (int nf = 0; nf < 2; ++nf) {
            short8_t bb;
            #pragma unroll
            for (int j = 0; j < 8; ++j)
                bb[j] = f2bf(w_tp0[(k0 * 32 + g * 8 + j) * 128 + w * 32 + nf * 16 + ln]);
            bfr[k0][nf] = bb;
        }

    const int base = blockIdx.x * 64;
    {
        const int e = tid >> 2, q = tid & 3;
        const int n = base + e;
        #pragma unroll
        for (int i = 0; i < 8; ++i) {
            float4 v = make_float4(0.f, 0.f, 0.f, 0.f);
            if (n < NN) v = *(const float4*)&h_final[(size_t)n * HF + q * 32 + i * 4];
            short4 s4; s4.x = f2bf(v.x); s4.y = f2bf(v.y); s4.z = f2bf(v.z); s4.w = f2bf(v.w);
            *(short4*)&sx[e][q * 32 + i * 4] = s4;
        }
    }
    __syncthreads();
    f32x4 acc[4][2];
    #pragma unroll
    for (int mf = 0; mf < 4; ++mf)
        #pragma unroll
        for (int nf = 0; nf < 2; ++nf)
            acc[mf][nf] = (f32x4){0.f, 0.f, 0.f, 0.f};
    #pragma unroll
    for (int k0 = 0; k0 < 4; ++k0) {
        short8_t a[4];
        #pragma unroll
        for (int mf = 0; mf < 4; ++mf)
            a[mf] = *(const short8_t*)&sx[mf * 16 + ln][k0 * 32 + g * 8];
        #pragma unroll
        for (int mf = 0; mf < 4; ++mf)
            #pragma unroll
            for (int nf = 0; nf < 2; ++nf)
                acc[mf][nf] = __builtin_amdgcn_mfma_f32_16x16x32_bf16(
                    a[mf], bfr[k0][nf], acc[mf][nf], 0, 0, 0);
    }
    #pragma unroll
    for (int mf = 0; mf < 4; ++mf)
        #pragma unroll
        for (int nf = 0; nf < 2; ++nf) {
            int col = w * 32 + nf * 16 + ln;
            #pragma unroll
            for (int r = 0; r < 4; ++r) {
                int n = base + mf * 16 + g * 4 + r;
                if (n < NN) Gb[(size_t)n * 128 + col] = f2bf(acc[mf][nf][r]);
            }
        }
}

// ---------------- K4b: Gv[n] = w_tp1 @ V_n (bf16 out) ----------------
__global__ __launch_bounds__(256) void k4b_gv(
    const float* __restrict__ h_final, const float* __restrict__ w_tp1,
    short* __restrict__ Gvb)
{
    __shared__ float sW1T[64 * 65];
    __shared__ float sv[4][192];
    const int tid = threadIdx.x, w = tid >> 6, lane = tid & 63;
    for (int idx = tid; idx < 4096; idx += 256) {
        int i = idx >> 6, j = idx & 63;
        sW1T[j * 65 + i] = w_tp1[idx];
    }
    for (int base = blockIdx.x * 4; base < NN; base += gridDim.x * 4) {
        __syncthreads();
        if (tid < 192) {
            int nd = tid / 48, c4 = tid % 48;
            int n = base + nd;
            float4 v = make_float4(0.f, 0.f, 0.f, 0.f);
            if (n < NN) v = *(const float4*)&h_final[(size_t)n * HF + 128 + c4 * 4];
            *(float4*)&sv[nd][c4 * 4] = v;
        }
        __syncthreads();
        int n = base + w;
        if (n < NN) {
            float a0 = 0.f, a1 = 0.f, a2 = 0.f;
            for (int j = 0; j < 64; ++j) {
                float wv = sW1T[j * 65 + lane];
                a0 = fmaf(wv, sv[w][3 * j],     a0);
                a1 = fmaf(wv, sv[w][3 * j + 1], a1);
                a2 = fmaf(wv, sv[w][3 * j + 2], a2);
            }
            short* gp = &Gvb[(size_t)n * 192 + lane * 3];
            gp[0] = f2bf(a0); gp[1] = f2bf(a1); gp[2] = f2bf(a2);
        }
    }
}

// ---------------- K4c: tp per target edge via two dots ----------------
__global__ __launch_bounds__(256) void k4c_dot(
    const float* __restrict__ h_final, const int* __restrict__ edge_index,
    const int* __restrict__ te,
    const short* __restrict__ Gb, const short* __restrict__ Gvb,
    float* __restrict__ tp)
{
    const int tid = threadIdx.x;
    const int e = blockIdx.x * 32 + (tid >> 3);
    const int sub = tid & 7;
    float s1 = 0.f, s2 = 0.f;
    if (e < ETT) {
        int gid = te[e];
        int r2 = edge_index[gid], c2 = edge_index[NE + gid];
        #pragma unroll
        for (int i = 0; i < 2; ++i) {
            short8_t gv = *(const short8_t*)&Gb[(size_t)r2 * 128 + sub * 16 + i * 8];
            float4 h0 = *(const float4*)&h_final[(size_t)c2 * HF + sub * 16 + i * 8];
            float4 h1 = *(const float4*)&h_final[(size_t)c2 * HF + sub * 16 + i * 8 + 4];
            s1 += bf2f(gv[0])*h0.x + bf2f(gv[1])*h0.y + bf2f(gv[2])*h0.z + bf2f(gv[3])*h0.w
                + bf2f(gv[4])*h1.x + bf2f(gv[5])*h1.y + bf2f(gv[6])*h1.z + bf2f(gv[7])*h1.w;
        }
        #pragma unroll
        for (int i = 0; i < 3; ++i) {
            short8_t gv = *(const short8_t*)&Gvb[(size_t)c2 * 192 + sub * 24 + i * 8];
            float4 h0 = *(const float4*)&h_final[(size_t)r2 * HF + 128 + sub * 24 + i * 8];
            float4 h1 = *(const float4*)&h_final[(size_t)r2 * HF + 128 + sub * 24 + i * 8 + 4];
            s2 += bf2f(gv[0])*h0.x + bf2f(gv[1])*h0.y + bf2f(gv[2])*h0.z + bf2f(gv[3])*h0.w
                + bf2f(gv[4])*h1.x + bf2f(gv[5])*h1.y + bf2f(gv[6])*h1.z + bf2f(gv[7])*h1.w;
        }
    }
    float res = s1 * (1.f / 128.f) + s2 * (1.f / 110.85125168440814f);
    res += __shfl_xor(res, 1); res += __shfl_xor(res, 2); res += __shfl_xor(res, 4);
    if (e < ETT && sub == 0) tp[e] = res;
}

// ---------------- K5: bond head, 2-stage MFMA ----------------
#define KP5 200
__global__ __launch_bounds__(256) void k5_mfma(
    const float* __restrict__ e_final, const int* __restrict__ te,
    const float* __restrict__ tp,
    const float* __restrict__ W_bh1, const float* __restrict__ b_bh1,
    const float* __restrict__ W_bh2, const float* __restrict__ b_bh2,
    float* __restrict__ out)
{
    __shared__ __align__(16) short sx[64][KP5];
    __shared__ __align__(16) short sy[64][136];
    const int tid = threadIdx.x, w = tid >> 6, lane = tid & 63, g = lane >> 4, ln = lane & 15;

    short8_t bfr[6][2];
    #pragma unroll
    for (int k0 = 0; k0 < 6; ++k0)
        #pragma unroll
        for (int nf = 0; nf < 2; ++nf) {
            short8_t bb;
            #pragma unroll
            for (int j = 0; j < 8; ++j) {
                int k = k0 * 32 + g * 8 + j;
                float v = 0.f;
                if (k < 160)       v = W_bh1[(size_t)(k + 1) * 128 + w * 32 + nf * 16 + ln];
                else if (k == 160) v = W_bh1[w * 32 + nf * 16 + ln];
                bb[j] = f2bf(v);
            }
            bfr[k0][nf] = bb;
        }
    const float bias0 = b_bh1[w * 32 + ln];
    const float bias1 = b_bh1[w * 32 + 16 + ln];

    short8_t bfr2[4];
    #pragma unroll
    for (int k0 = 0; k0 < 4; ++k0) {
        short8_t bb;
        #pragma unroll
        for (int j = 0; j < 8; ++j) {
            int k = k0 * 32 + g * 8 + j;
            bb[j] = (ln < 8) ? f2bf(W_bh2[k * 8 + ln]) : (short)0;
        }
        bfr2[k0] = bb;
    }
    const float b2o = (ln < 8) ? b_bh2[ln] : 0.f;

    const int base = blockIdx.x * 64;
    for (int idx = tid; idx < 64 * 39; idx += 256) {
        int rr = idx / 39, c = 161 + idx % 39;
        sx[rr][c] = 0;
    }
    {
        const int e = tid >> 2, q = tid & 3;
        const int ge = base + e;
        const bool valid = (ge < ETT);
        const int gid = valid ? te[ge] : 0;
        #pragma unroll
        for (int i = 0; i < 10; ++i) {
            float4 v = make_float4(0.f, 0.f, 0.f, 0.f);
            if (valid) v = *(const float4*)&e_final[(size_t)gid * EFW + q * 40 + i * 4];
            short4 s4; s4.x = f2bf(v.x); s4.y = f2bf(v.y); s4.z = f2bf(v.z); s4.w = f2bf(v.w);
            *(short4*)&sx[e][q * 40 + i * 4] = s4;
        }
    }
    if (tid < 64) {
        int ge = base + tid;
        sx[tid][160] = f2bf((ge < ETT) ? tp[ge] : 0.f);
    }
    __syncthreads();

    f32x4 acc[4][2];
    #pragma unroll
    for (int mf = 0; mf < 4; ++mf)
        #pragma unroll
        for (int nf = 0; nf < 2; ++nf)
            acc[mf][nf] = (f32x4){0.f, 0.f, 0.f, 0.f};
    #pragma unroll
    for (int k0 = 0; k0 < 6; ++k0) {
        short8_t a[4];
        #pragma unroll
        for (int mf = 0; mf < 4; ++mf)
            a[mf] = *(const short8_t*)&sx[mf * 16 + ln][k0 * 32 + g * 8];
        #pragma unroll
        for (int mf = 0; mf < 4; ++mf)
            #pragma unroll
            for (int nf = 0; nf < 2; ++nf)
                acc[mf][nf] = __builtin_amdgcn_mfma_f32_16x16x32_bf16(
                    a[mf], bfr[k0][nf], acc[mf][nf], 0, 0, 0);
    }
    #pragma unroll
    for (int mf = 0; mf < 4; ++mf)
        #pragma unroll
        for (int nf = 0; nf < 2; ++nf)
            #pragma unroll
            for (int r = 0; r < 4; ++r)
                sy[mf * 16 + g * 4 + r][w * 32 + nf * 16 + ln] =
                    f2bf(silu_f(acc[mf][nf][r] + (nf ? bias1 : bias0)));
    __syncthreads();

    f32x4 z = (f32x4){0.f, 0.f, 0.f, 0.f};
    #pragma unroll
    for (int k0 = 0; k0 < 4; ++k0) {
        short8_t a2 = *(const short8_t*)&sy[w * 16 + ln][k0 * 32 + g * 8];
        z = __builtin_amdgcn_mfma_f32_16x16x32_bf16(a2, bfr2[k0], z, 0, 0, 0);
    }
    #pragma unroll
    for (int r = 0; r < 4; ++r) {
        int e = base + w * 16 + g * 4 + r;
        if (ln < 8 && e < ETT) out[(size_t)e * 8 + ln] = z[r] + b2o;
    }
}

// ---------------- K6: predicted_r0 gather ----------------
__global__ void k6_r0(const float* __restrict__ r_t, const float* __restrict__ delta,
                      const int* __restrict__ tn, float* __restrict__ out)
{
    int i = blockIdx.x * 256 + threadIdx.x;
    if (i < NTT * 3) {
        int t = i / 3, d = i - t * 3;
        int n = tn[t];
        out[i] = r_t[n * 3 + d] + delta[n * 3 + d];
    }
}

extern "C" void kernel_launch(void* const* d_in, const int* in_sizes, int n_in,
                              void* d_out, int out_size, void* d_ws, size_t ws_size,
                              hipStream_t stream)
{
    const float* h_final = (const float*)d_in[0];
    const float* e_final = (const float*)d_in[1];
    const float* r_t     = (const float*)d_in[2];
    const int*   tn      = (const int*)d_in[3];
    const int*   te      = (const int*)d_in[4];
    const int*   ei      = (const int*)d_in[5];
    const float* W_nsp   = (const float*)d_in[6];
    const float* b_nsp   = (const float*)d_in[7];
    const float* W_at1   = (const float*)d_in[8];
    const float* b_at1   = (const float*)d_in[9];
    const float* W_at2   = (const float*)d_in[10];
    const float* b_at2   = (const float*)d_in[11];
    const float* W_left  = (const float*)d_in[12];
    const float* b_left  = (const float*)d_in[13];
    const float* W_right = (const float*)d_in[14];
    const float* b_right = (const float*)d_in[15];
    const float* W_el1   = (const float*)d_in[16];
    const float* b_el1   = (const float*)d_in[17];
    const float* ln_g    = (const float*)d_in[18];
    const float* ln_b    = (const float*)d_in[19];
    const float* W_el2   = (const float*)d_in[20];
    const float* b_el2   = (const float*)d_in[21];
    const float* w_tp0   = (const float*)d_in[22];
    const float* w_tp1   = (const float*)d_in[23];
    const float* W_bh1   = (const float*)d_in[24];
    const float* b_bh1   = (const float*)d_in[25];
    const float* W_bh2   = (const float*)d_in[26];
    const float* b_bh2   = (const float*)d_in[27];

    float* ws    = (float*)d_ws;
    float* Wl    = ws;                         // 16384
    float* bl    = Wl + 16384;                 // 128
    float* Wr    = bl + 128;                   // 16384
    float* br    = Wr + 16384;                 // 128   -> 33024
    float* Wc1   = ws + 33024;                 // 16384
    float* bc1   = Wc1 + 16384;                // 128   -> 49536
    short* hlb   = (short*)(ws + 49536);       // 6.4M shorts
    short* hrb   = hlb + 6400000;              // 6.4M shorts
    short* Xn    = hrb + 6400000;              // 16M shorts
    float* delta = (float*)(Xn + 16000000);    // 150000
    float* tpb   = delta + 150000;             // 100000
    short* Gvb   = (short*)(tpb + 100000);     // 9.6M shorts
    short* Gb    = hlb;                        // alias (reused after k3)

    float* out      = (float*)d_out;
    float* out_atom = out;                     // 10000*32
    float* out_r0   = out + 320000;            // 10000*3
    float* out_bond = out + 350000;            // 100000*8

    k0_all<<<128, 256, 0, stream>>>(W_nsp, b_nsp, W_left, b_left, W_right, b_right,
                                    W_at1, b_at1, Wl, bl, Wr, br, Wc1, bc1);
    k3pre<<<15625, 256, 0, stream>>>(e_final, Xn);
    k1_mfma<<<782, 256, 0, stream>>>(h_final, Wl, bl, Wr, br, hlb, hrb);
    k2_mfma<<<157, 256, 0, stream>>>(h_final, tn, Wc1, bc1, W_at2, b_at2, out_atom);
    hipMemsetAsync(delta, 0, 150000 * sizeof(float), stream);
    k3_edge<<<GRID3, 512, 0, stream>>>(e_final, ei, Xn, hlb, hrb, r_t, W_el1, b_el1,
                                       ln_g, ln_b, W_el2, b_el2, delta);
    k6_r0<<<(NTT * 3 + 255) / 256, 256, 0, stream>>>(r_t, delta, tn, out_r0);
    k4a_g<<<782, 256, 0, stream>>>(h_final, w_tp0, Gb);
    k4b_gv<<<2048, 256, 0, stream>>>(h_final, w_tp1, Gvb);
    k4c_dot<<<3125, 256, 0, stream>>>(h_final, ei, te, Gb, Gvb, tpb);
    k5_mfma<<<1563, 256, 0, stream>>>(e_final, te, tpb, W_bh1, b_bh1, W_bh2, b_bh2, out_bond);
}

// Round 13
// 463.707 us; speedup vs baseline: 1.0927x; 1.0927x over previous
//
#include <hip/hip_runtime.h>
#include <math.h>

#define NN   50000
#define NE   500000
#define NTT  10000
#define ETT  100000
#define HF   320      // h_final row = 128 + 3*64
#define EFW  160      // e_final row = 64 + 3*32
#define NT3  7813     // ceil(NE/64)
#define GRID3 1024

typedef __attribute__((ext_vector_type(8))) short short8_t;
typedef __attribute__((ext_vector_type(4))) float f32x4;

__device__ __forceinline__ float silu_f(float x) { return x / (1.f + __expf(-x)); }

__device__ __forceinline__ short f2bf(float f) {
    unsigned u = __float_as_uint(f);
    unsigned r = (u + 0x7fffu + ((u >> 16) & 1u)) >> 16;
    return (short)r;
}
__device__ __forceinline__ float bf2f(short s) {
    return __uint_as_float(((unsigned)(unsigned short)s) << 16);
}
// XOR swizzle helpers: return SHORT index. stride 256 shorts (512B) / 128 shorts (256B)
__device__ __forceinline__ int swz256(int row, int col) {
    return row * 256 + (((col << 1) ^ ((row & 7) << 4)) >> 1);
}
__device__ __forceinline__ int swz128(int row, int col) {
    return row * 128 + (((col << 1) ^ ((row & 7) << 4)) >> 1);
}

// ---------------- K0: fold W_nsp into W_left/W_right AND W_nsp@W_at1 ----------------
__global__ __launch_bounds__(256) void k0_all(
    const float* __restrict__ W_nsp, const float* __restrict__ b_nsp,
    const float* __restrict__ W_left, const float* __restrict__ b_left,
    const float* __restrict__ W_right, const float* __restrict__ b_right,
    const float* __restrict__ W_at1, const float* __restrict__ b_at1,
    float* __restrict__ Wl, float* __restrict__ bl,
    float* __restrict__ Wr, float* __restrict__ br,
    float* __restrict__ Wc1, float* __restrict__ bc1)
{
    if (blockIdx.x < 64) {
        int idx = blockIdx.x * 256 + threadIdx.x;
        int i = idx >> 7, j = idx & 127;
        float al = 0.f, ar = 0.f;
        for (int k = 0; k < 128; ++k) {
            float w = W_nsp[i * 128 + k];
            al = fmaf(w, W_left[k * 128 + j], al);
            ar = fmaf(w, W_right[k * 128 + j], ar);
        }
        Wl[idx] = al; Wr[idx] = ar;
        if (i == 0) {
            float cl = 0.f, cr = 0.f;
            for (int k = 0; k < 128; ++k) {
                float bn = b_nsp[k];
                cl = fmaf(bn, W_left[k * 128 + j], cl);
                cr = fmaf(bn, W_right[k * 128 + j], cr);
            }
            bl[j] = cl + b_left[j];
            br[j] = cr + b_right[j];
        }
    } else {
        int idx = (blockIdx.x - 64) * 256 + threadIdx.x;
        int i = idx >> 7, j = idx & 127;
        float a = 0.f;
        for (int k = 0; k < 128; ++k)
            a = fmaf(W_nsp[i * 128 + k], W_at1[k * 128 + j], a);
        Wc1[idx] = a;
        if (i == 0) {
            float c = 0.f;
            for (int k = 0; k < 128; ++k)
                c = fmaf(b_nsp[k], W_at1[k * 128 + j], c);
            bc1[j] = c + b_at1[j];
        }
    }
}

// ---------------- K1: hl/hr via MFMA, bf16 outputs ----------------
#define KP1 136
__global__ __launch_bounds__(256) void k1_mfma(
    const float* __restrict__ h_final,
    const float* __restrict__ Wl, const float* __restrict__ bl,
    const float* __restrict__ Wr, const float* __restrict__ br,
    short* __restrict__ hlb, short* __restrict__ hrb)
{
    __shared__ __align__(16) short sx[64][KP1];
    const int tid = threadIdx.x;
    const int w = tid >> 6, lane = tid & 63, g = lane >> 4, ln = lane & 15;

    short8_t bfr[4][4];
    float bias[4];
    #pragma unroll
    for (int nf = 0; nf < 4; ++nf) {
        int col = w * 64 + nf * 16 + ln;
        const float* Wsrc = (col < 128) ? Wl : Wr;
        int cc = col & 127;
        bias[nf] = (col < 128) ? bl[cc] : br[cc];
        #pragma unroll
        for (int k0 = 0; k0 < 4; ++k0) {
            short8_t bb;
            #pragma unroll
            for (int j = 0; j < 8; ++j)
                bb[j] = f2bf(Wsrc[(k0 * 32 + g * 8 + j) * 128 + cc]);
            bfr[k0][nf] = bb;
        }
    }

    const int base = blockIdx.x * 64;
    {
        const int e = tid >> 2, q = tid & 3;
        const int n = base + e;
        #pragma unroll
        for (int i = 0; i < 8; ++i) {
            float4 v = make_float4(0.f, 0.f, 0.f, 0.f);
            if (n < NN) v = *(const float4*)&h_final[(size_t)n * HF + q * 32 + i * 4];
            short4 s4; s4.x = f2bf(v.x); s4.y = f2bf(v.y); s4.z = f2bf(v.z); s4.w = f2bf(v.w);
            *(short4*)&sx[e][q * 32 + i * 4] = s4;
        }
    }
    __syncthreads();
    f32x4 acc[4][4];
    #pragma unroll
    for (int mf = 0; mf < 4; ++mf)
        #pragma unroll
        for (int nf = 0; nf < 4; ++nf)
            acc[mf][nf] = (f32x4){0.f, 0.f, 0.f, 0.f};
    #pragma unroll
    for (int k0 = 0; k0 < 4; ++k0) {
        short8_t a[4];
        #pragma unroll
        for (int mf = 0; mf < 4; ++mf)
            a[mf] = *(const short8_t*)&sx[mf * 16 + ln][k0 * 32 + g * 8];
        #pragma unroll
        for (int mf = 0; mf < 4; ++mf)
            #pragma unroll
            for (int nf = 0; nf < 4; ++nf)
                acc[mf][nf] = __builtin_amdgcn_mfma_f32_16x16x32_bf16(
                    a[mf], bfr[k0][nf], acc[mf][nf], 0, 0, 0);
    }
    #pragma unroll
    for (int mf = 0; mf < 4; ++mf)
        #pragma unroll
        for (int nf = 0; nf < 4; ++nf) {
            int col = w * 64 + nf * 16 + ln;
            #pragma unroll
            for (int r = 0; r < 4; ++r) {
                int n = base + mf * 16 + g * 4 + r;
                if (n < NN) {
                    short v = f2bf(acc[mf][nf][r] + bias[nf]);
                    if (col < 128) hlb[(size_t)n * 128 + col] = v;
                    else           hrb[(size_t)n * 128 + col - 128] = v;
                }
            }
        }
}

// ---------------- K2: atom head via folded MFMA (x@Wc1 -> silu -> @W_at2) ----------------
__global__ __launch_bounds__(256) void k2_mfma(
    const float* __restrict__ h_final, const int* __restrict__ tn,
    const float* __restrict__ Wc1, const float* __restrict__ bc1,
    const float* __restrict__ W_at2, const float* __restrict__ b_at2,
    float* __restrict__ out)
{
    __shared__ __align__(16) short sxf[64 * 128];
    __shared__ __align__(16) short syf[64 * 128];
    const int tid = threadIdx.x;
    const int w = tid >> 6, lane = tid & 63, g = lane >> 4, ln = lane & 15;

    short8_t bfr1[4][2];
    float biasc[2];
    #pragma unroll
    for (int nf = 0; nf < 2; ++nf) {
        int col = w * 32 + nf * 16 + ln;
        biasc[nf] = bc1[col];
        #pragma unroll
        for (int k0 = 0; k0 < 4; ++k0) {
            short8_t bb;
            #pragma unroll
            for (int j = 0; j < 8; ++j)
                bb[j] = f2bf(Wc1[(k0 * 32 + g * 8 + j) * 128 + col]);
            bfr1[k0][nf] = bb;
        }
    }
    short8_t bfr2[4][2];
    float ba2v[2];
    #pragma unroll
    for (int nf = 0; nf < 2; ++nf) {
        ba2v[nf] = b_at2[nf * 16 + ln];
        #pragma unroll
        for (int k0 = 0; k0 < 4; ++k0) {
            short8_t bb;
            #pragma unroll
            for (int j = 0; j < 8; ++j)
                bb[j] = f2bf(W_at2[(k0 * 32 + g * 8 + j) * 32 + nf * 16 + ln]);
            bfr2[k0][nf] = bb;
        }
    }

    const int base = blockIdx.x * 64;
    {
        const int e = tid >> 2, q = tid & 3;
        const int t = base + e;
        const bool valid = (t < NTT);
        const int node = valid ? tn[t] : 0;
        #pragma unroll
        for (int i = 0; i < 8; ++i) {
            float4 v = make_float4(0.f, 0.f, 0.f, 0.f);
            if (valid) v = *(const float4*)&h_final[(size_t)node * HF + q * 32 + i * 4];
            short4 s4; s4.x = f2bf(v.x); s4.y = f2bf(v.y); s4.z = f2bf(v.z); s4.w = f2bf(v.w);
            *(short4*)&sxf[swz128(e, q * 32 + i * 4)] = s4;
        }
    }
    __syncthreads();
    f32x4 acc[4][2];
    #pragma unroll
    for (int mf = 0; mf < 4; ++mf)
        #pragma unroll
        for (int nf = 0; nf < 2; ++nf)
            acc[mf][nf] = (f32x4){0.f, 0.f, 0.f, 0.f};
    #pragma unroll
    for (int k0 = 0; k0 < 4; ++k0) {
        short8_t a[4];
        #pragma unroll
        for (int mf = 0; mf < 4; ++mf)
            a[mf] = *(const short8_t*)&sxf[swz128(mf * 16 + ln, k0 * 32 + g * 8)];
        #pragma unroll
        for (int mf = 0; mf < 4; ++mf)
            #pragma unroll
            for (int nf = 0; nf < 2; ++nf)
                acc[mf][nf] = __builtin_amdgcn_mfma_f32_16x16x32_bf16(
                    a[mf], bfr1[k0][nf], acc[mf][nf], 0, 0, 0);
    }
    #pragma unroll
    for (int mf = 0; mf < 4; ++mf)
        #pragma unroll
        for (int nf = 0; nf < 2; ++nf)
            #pragma unroll
            for (int r = 0; r < 4; ++r)
                syf[swz128(mf * 16 + g * 4 + r, w * 32 + nf * 16 + ln)] =
                    f2bf(silu_f(acc[mf][nf][r] + biasc[nf]));
    __syncthreads();
    f32x4 z[2];
    z[0] = (f32x4){0.f,0.f,0.f,0.f}; z[1] = (f32x4){0.f,0.f,0.f,0.f};
    #pragma unroll
    for (int k0 = 0; k0 < 4; ++k0) {
        short8_t a2 = *(const short8_t*)&syf[swz128(w * 16 + ln, k0 * 32 + g * 8)];
        #pragma unroll
        for (int nf = 0; nf < 2; ++nf)
            z[nf] = __builtin_amdgcn_mfma_f32_16x16x32_bf16(a2, bfr2[k0][nf], z[nf], 0, 0, 0);
    }
    #pragma unroll
    for (int nf = 0; nf < 2; ++nf)
        #pragma unroll
        for (int r = 0; r < 4; ++r) {
            int t = base + w * 16 + g * 4 + r;
            if (t < NTT) out[(size_t)t * 32 + nf * 16 + ln] = z[nf][r] + ba2v[nf];
        }
}

// ---------------- K3pre: per-edge vector norms -> bf16 Xn[NE][32] ----------------
__global__ __launch_bounds__(256) void k3pre(
    const float* __restrict__ e_final, short* __restrict__ Xn)
{
    const int tid = threadIdx.x;
    const int e = blockIdx.x * 32 + (tid >> 3);
    const int sub = tid & 7;
    const float* p = &e_final[(size_t)e * EFW + 64 + sub * 12];
    float4 a = *(const float4*)p;
    float4 b = *(const float4*)(p + 4);
    float4 c = *(const float4*)(p + 8);
    short4 o;
    o.x = f2bf(sqrtf(a.x*a.x + a.y*a.y + a.z*a.z));
    o.y = f2bf(sqrtf(a.w*a.w + b.x*b.x + b.y*b.y));
    o.z = f2bf(sqrtf(b.z*b.z + b.w*b.w + c.x*c.x));
    o.w = f2bf(sqrtf(c.y*c.y + c.z*c.z + c.w*c.w));
    *(short4*)&Xn[(size_t)e * 32 + sub * 4] = o;
}

// ---------------- K3: edge MLP, 8-wave blocks (round-10 version, known-good) ----------------
__global__ __launch_bounds__(512, 4) void k3_edge(
    const float* __restrict__ e_final, const int* __restrict__ edge_index,
    const short* __restrict__ Xn,
    const short* __restrict__ hlb, const short* __restrict__ hrb,
    const float* __restrict__ r_t,
    const float* __restrict__ W_el1, const float* __restrict__ b_el1,
    const float* __restrict__ ln_g, const float* __restrict__ ln_b,
    const float* __restrict__ W_el2, const float* __restrict__ b_el2,
    float* __restrict__ delta)
{
    __shared__ __align__(16) short sxf[64 * 256];   // 32 KB, XOR-swizzled, K=224 used
    __shared__ float sstat[64][8][2];               // per-wave LN partials
    __shared__ float smu[64][2];
    __shared__ float spd[64][8];
    __shared__ float srel[64][4];
    __shared__ int   sidx[64];

    const int tid  = threadIdx.x;
    const int w    = tid >> 6;       // wave 0..7 -> cols [w*16, w*16+16)
    const int lane = tid & 63;
    const int g    = lane >> 4;
    const int ln   = lane & 15;
    const int es   = tid >> 3, qs = tid & 7;   // staging: 8 threads per edge

    // B fragments of W_el1 (224x128), one 16-col slice per wave
    short8_t bfr[7];
    #pragma unroll
    for (int k0 = 0; k0 < 7; ++k0) {
        short8_t bb;
        #pragma unroll
        for (int j = 0; j < 8; ++j)
            bb[j] = f2bf(W_el1[(k0 * 32 + g * 8 + j) * 128 + w * 16 + ln]);
        bfr[k0] = bb;
    }
    const float bias0 = b_el1[w * 16 + ln];
    const float gj0   = ln_g[w * 16 + ln];
    const float bj0   = ln_b[w * 16 + ln];
    const float w2j0  = W_el2[w * 16 + ln];
    const float b2 = b_el2[0];

    for (int t = blockIdx.x; t < NT3; t += GRID3) {
        __syncthreads();   // sxf & partial arrays free

        // ---- direct gather staging into swizzled sxf ----
        {
            const int ge = t * 64 + es;
            const bool valid = (ge < NE);
            int r = 0, c = 0;
            if (valid) { r = edge_index[ge]; c = edge_index[NE + ge]; }
            // e_scalar cols qs*8..+8
            #pragma unroll
            for (int i = 0; i < 2; ++i) {
                float4 v = make_float4(0.f, 0.f, 0.f, 0.f);
                if (valid) v = *(const float4*)&e_final[(size_t)ge * EFW + qs * 8 + i * 4];
                short4 s4; s4.x = f2bf(v.x); s4.y = f2bf(v.y);
                s4.z = f2bf(v.z); s4.w = f2bf(v.w);
                *(short4*)&sxf[swz256(es, qs * 8 + i * 4)] = s4;
            }
            // norms col 64+qs*4 (precomputed bf16)
            {
                short4 n0 = make_short4(0,0,0,0);
                if (valid) n0 = *(const short4*)&Xn[(size_t)ge * 32 + qs * 4];
                *(short4*)&sxf[swz256(es, 64 + qs * 4)] = n0;
            }
            // inter cols 96+qs*16..+16
            #pragma unroll
            for (int i = 0; i < 2; ++i) {
                short8_t hv, rv, pr;
                if (valid) {
                    hv = *(const short8_t*)&hlb[(size_t)r * 128 + qs * 16 + i * 8];
                    rv = *(const short8_t*)&hrb[(size_t)c * 128 + qs * 16 + i * 8];
                } else {
                    #pragma unroll
                    for (int jj = 0; jj < 8; ++jj) { hv[jj] = 0; rv[jj] = 0; }
                }
                #pragma unroll
                for (int jj = 0; jj < 8; ++jj)
                    pr[jj] = f2bf(bf2f(hv[jj]) * bf2f(rv[jj]));
                *(short8_t*)&sxf[swz256(es, 96 + qs * 16 + i * 8)] = pr;
            }
            if (qs == 0) {
                float rx = 0.f, ry = 0.f, rz = 0.f;
                if (valid) {
                    rx = r_t[r*3+0] - r_t[c*3+0];
                    ry = r_t[r*3+1] - r_t[c*3+1];
                    rz = r_t[r*3+2] - r_t[c*3+2];
                }
                sidx[es] = r;
                srel[es][0] = rx; srel[es][1] = ry; srel[es][2] = rz;
            }
        }
        __syncthreads();

        // ---- MFMA: y[64][16-slice] = x[64][224] @ W[:, w*16..+16) ----
        f32x4 acc[4];
        #pragma unroll
        for (int mf = 0; mf < 4; ++mf)
            acc[mf] = (f32x4){0.f, 0.f, 0.f, 0.f};
        #pragma unroll
        for (int k0 = 0; k0 < 7; ++k0) {
            short8_t a[4];
            #pragma unroll
            for (int mf = 0; mf < 4; ++mf)
                a[mf] = *(const short8_t*)&sxf[swz256(mf * 16 + ln, k0 * 32 + g * 8)];
            #pragma unroll
            for (int mf = 0; mf < 4; ++mf)
                acc[mf] = __builtin_amdgcn_mfma_f32_16x16x32_bf16(
                    a[mf], bfr[k0], acc[mf], 0, 0, 0);
        }

        // ---- LN stats: butterfly over this wave's 16 cols, cross-wave via LDS ----
        float mysum = 0.f, mysq = 0.f;
        #pragma unroll
        for (int mf = 0; mf < 4; ++mf)
            #pragma unroll
            for (int r = 0; r < 4; ++r) {
                float y0 = acc[mf][r] + bias0;
                float s = y0;
                float q = y0 * y0;
                s += __shfl_xor(s, 1); q += __shfl_xor(q, 1);
                s += __shfl_xor(s, 2); q += __shfl_xor(q, 2);
                s += __shfl_xor(s, 4); q += __shfl_xor(q, 4);
                s += __shfl_xor(s, 8); q += __shfl_xor(q, 8);
                if (ln == mf * 4 + r) { mysum = s; mysq = q; }
            }
        {
            int row = (ln >> 2) * 16 + g * 4 + (ln & 3);
            *(float2*)&sstat[row][w][0] = make_float2(mysum, mysq);
        }
        __syncthreads();
        if (tid < 64) {
            float S = 0.f, Q = 0.f;
            #pragma unroll
            for (int i = 0; i < 4; ++i) {
                float4 s4 = *(const float4*)&sstat[tid][i * 2][0];
                S += s4.x + s4.z;
                Q += s4.y + s4.w;
            }
            float mu = S * (1.f / 128.f);
            float iv = rsqrtf(Q * (1.f / 128.f) - mu * mu + 1e-5f);
            *(float2*)&smu[tid][0] = make_float2(mu, iv);
        }
        __syncthreads();

        // ---- silu dot partials ----
        float mydot = 0.f;
        #pragma unroll
        for (int mf = 0; mf < 4; ++mf)
            #pragma unroll
            for (int r = 0; r < 4; ++r) {
                float2 mi = *(const float2*)&smu[mf * 16 + g * 4 + r][0];
                float y0 = acc[mf][r] + bias0;
                float p = silu_f((y0 - mi.x) * mi.y * gj0 + bj0) * w2j0;
                p += __shfl_xor(p, 1); p += __shfl_xor(p, 2);
                p += __shfl_xor(p, 4); p += __shfl_xor(p, 8);
                if (ln == mf * 4 + r) mydot = p;
            }
        {
            int row = (ln >> 2) * 16 + g * 4 + (ln & 3);
            spd[row][w] = mydot;
        }
        __syncthreads();
        if (tid < 64) {
            int ge = t * 64 + tid;
            if (ge < NE) {
                float4 p4a = *(const float4*)&spd[tid][0];
                float4 p4b = *(const float4*)&spd[tid][4];
                float we = p4a.x + p4a.y + p4a.z + p4a.w
                         + p4b.x + p4b.y + p4b.z + p4b.w + b2;
                float rx = srel[tid][0], ry = srel[tid][1], rz = srel[tid][2];
                float d = sqrtf(rx*rx + ry*ry + rz*rz) + 1e-8f;
                float f = we / (d * (d + 1.f));
                int rr = sidx[tid];
                atomicAdd(&delta[rr*3+0], f*rx);
                atomicAdd(&delta[rr*3+1], f*ry);
                atomicAdd(&delta[rr*3+2], f*rz);
            }
        }
    }
}

// ---------------- K4a: G = H_s @ w_tp0 (bf16 out) ----------------
__global__ __launch_bounds__(256) void k4a_g(
    const float* __restrict__ h_final, const float* __restrict__ w_tp0,
    short* __restrict__ Gb)
{
    __shared__ __align__(16) short sx[64][KP1];
    const int tid = threadIdx.x;
    const int w = tid >> 6, lane = tid & 63, g = lane >> 4, ln = lane & 15;

    short8_t bfr[4][2];
    #pragma unroll
    for (int k0 = 0; k0 < 4; ++k0)
        #pragma unroll
        for (int nf = 0; nf < 2; ++nf) {
            short8_t bb;
            #pragma unroll
            for (int j = 0; j < 8; ++j)
                bb[j] = f2bf(w_tp0[(k0 * 32 + g * 8 + j) * 128 + w * 32 + nf * 16 + ln]);
            bfr[k0][nf] = bb;
        }

    const int base = blockIdx.x * 64;
    {
        const int e = tid >> 2, q = tid & 3;
        const int n = base + e;
        #pragma unroll
        for (int i = 0; i < 8; ++i) {
            float4 v = make_float4(0.f, 0.f, 0.f, 0.f);
            if (n < NN) v = *(const float4*)&h_final[(size_t)n * HF + q * 32 + i * 4];
            short4 s4; s4.x = f2bf(v.x); s4.y = f2bf(v.y); s4.z = f2bf(v.z); s4.w = f2bf(v.w);
            *(short4*)&sx[e][q * 32 + i * 4] = s4;
        }
    }
    __syncthreads();
    f32x4 acc[4][2];
    #pragma unroll
    for (int mf = 0; mf < 4; ++mf)
        #pragma unroll
        for (int nf = 0; nf < 2; ++nf)
            acc[mf][nf] = (f32x4){0.f, 0.f, 0.f, 0.f};
    #pragma unroll
    for (int k0 = 0; k0 < 4; ++k0) {
        short8_t a[4];
        #pragma unroll
        for (int mf = 0; mf < 4; ++mf)
            a[mf] = *(const short8_t*)&sx[mf * 16 + ln][k0 * 32 + g * 8];
        #pragma unroll
        for (int mf = 0; mf < 4; ++mf)
            #pragma unroll
            for (int nf = 0; nf < 2; ++nf)
                acc[mf][nf] = __builtin_amdgcn_mfma_f32_16x16x32_bf16(
                    a[mf], bfr[k0][nf], acc[mf][nf], 0, 0, 0);
    }
    #pragma unroll
    for (int mf = 0; mf < 4; ++mf)
        #pragma unroll
        for (int nf = 0; nf < 2; ++nf) {
            int col = w * 32 + nf * 16 + ln;
            #pragma unroll
            for (int r = 0; r < 4; ++r) {
                int n = base + mf * 16 + g * 4 + r;
                if (n < NN) Gb[(size_t)n * 128 + col] = f2bf(acc[mf][nf][r]);
            }
        }
}

// ---------------- K4b: Gv[n] = w_tp1 @ V_n (bf16 out) ----------------
__global__ __launch_bounds__(256) void k4b_gv(
    const float* __restrict__ h_final, const float* __restrict__ w_tp1,
    short* __restrict__ Gvb)
{
    __shared__ float sW1T[64 * 65];
    __shared__ float sv[4][192];
    const int tid = threadIdx.x, w = tid >> 6, lane = tid & 63;
    for (int idx = tid; idx < 4096; idx += 256) {
        int i = idx >> 6, j = idx & 63;
        sW1T[j * 65 + i] = w_tp1[idx];
    }
    for (int base = blockIdx.x * 4; base < NN; base += gridDim.x * 4) {
        __syncthreads();
        if (tid < 192) {
            int nd = tid / 48, c4 = tid % 48;
            int n = base + nd;
            float4 v = make_float4(0.f, 0.f, 0.f, 0.f);
            if (n < NN) v = *(const float4*)&h_final[(size_t)n * HF + 128 + c4 * 4];
            *(float4*)&sv[nd][c4 * 4] = v;
        }
        __syncthreads();
        int n = base + w;
        if (n < NN) {
            float a0 = 0.f, a1 = 0.f, a2 = 0.f;
            for (int j = 0; j < 64; ++j) {
                float wv = sW1T[j * 65 + lane];
                a0 = fmaf(wv, sv[w][3 * j],     a0);
                a1 = fmaf(wv, sv[w][3 * j + 1], a1);
                a2 = fmaf(wv, sv[w][3 * j + 2], a2);
            }
            short* gp = &Gvb[(size_t)n * 192 + lane * 3];
            gp[0] = f2bf(a0); gp[1] = f2bf(a1); gp[2] = f2bf(a2);
        }
    }
}

// ---------------- K5: bond head, tp inline (merged k4c) + 2-stage MFMA ----------------
#define KP5 200
__global__ __launch_bounds__(256) void k5_mfma(
    const float* __restrict__ e_final, const int* __restrict__ te,
    const float* __restrict__ h_final, const int* __restrict__ edge_index,
    const short* __restrict__ Gb, const short* __restrict__ Gvb,
    const float* __restrict__ W_bh1, const float* __restrict__ b_bh1,
    const float* __restrict__ W_bh2, const float* __restrict__ b_bh2,
    float* __restrict__ out)
{
    __shared__ __align__(16) short sx[64][KP5];
    __shared__ __align__(16) short sy[64][136];
    __shared__ float stp[64];
    const int tid = threadIdx.x, w = tid >> 6, lane = tid & 63, g = lane >> 4, ln = lane & 15;
    const int base = blockIdx.x * 64;

    // ---- inline tp (was k4c): 4 threads per edge ----
    {
        const int e = tid >> 2, q = tid & 3;
        const int ge = base + e;
        const bool valid = (ge < ETT);
        const int gid = valid ? te[ge] : 0;
        const int r2 = edge_index[gid], c2 = edge_index[NE + gid];
        float s1 = 0.f, s2 = 0.f;
        #pragma unroll
        for (int i = 0; i < 4; ++i) {
            short8_t gv = *(const short8_t*)&Gb[(size_t)r2 * 128 + q * 32 + i * 8];
            float4 h0 = *(const float4*)&h_final[(size_t)c2 * HF + q * 32 + i * 8];
            float4 h1 = *(const float4*)&h_final[(size_t)c2 * HF + q * 32 + i * 8 + 4];
            s1 += bf2f(gv[0])*h0.x + bf2f(gv[1])*h0.y + bf2f(gv[2])*h0.z + bf2f(gv[3])*h0.w
                + bf2f(gv[4])*h1.x + bf2f(gv[5])*h1.y + bf2f(gv[6])*h1.z + bf2f(gv[7])*h1.w;
        }
        #pragma unroll
        for (int i = 0; i < 6; ++i) {
            short8_t gv = *(const short8_t*)&Gvb[(size_t)c2 * 192 + q * 48 + i * 8];
            float4 h0 = *(const float4*)&h_final[(size_t)r2 * HF + 128 + q * 48 + i * 8];
            float4 h1 = *(const float4*)&h_final[(size_t)r2 * HF + 128 + q * 48 + i * 8 + 4];
            s2 += bf2f(gv[0])*h0.x + bf2f(gv[1])*h0.y + bf2f(gv[2])*h0.z + bf2f(gv[3])*h0.w
                + bf2f(gv[4])*h1.x + bf2f(gv[5])*h1.y + bf2f(gv[6])*h1.z + bf2f(gv[7])*h1.w;
        }
        float res = s1 * (1.f / 128.f) + s2 * (1.f / 110.85125168440814f);
        res += __shfl_xor(res, 1); res += __shfl_xor(res, 2);
        if (q == 0) stp[e] = res;
    }

    short8_t bfr[6][2];
    #pragma unroll
    for (int k0 = 0; k0 < 6; ++k0)
        #pragma unroll
        for (int nf = 0; nf < 2; ++nf) {
            short8_t bb;
            #pragma unroll
            for (int j = 0; j < 8; ++j) {
                int k = k0 * 32 + g * 8 + j;
                float v = 0.f;
                if (k < 160)       v = W_bh1[(size_t)(k + 1) * 128 + w * 32 + nf * 16 + ln];
                else if (k == 160) v = W_bh1[w * 32 + nf * 16 + ln];
                bb[j] = f2bf(v);
            }
            bfr[k0][nf] = bb;
        }
    const float bias0 = b_bh1[w * 32 + ln];
    const float bias1 = b_bh1[w * 32 + 16 + ln];

    short8_t bfr2[4];
    #pragma unroll
    for (int k0 = 0; k0 < 4; ++k0) {
        short8_t bb;
        #pragma unroll
        for (int j = 0; j < 8; ++j) {
            int k = k0 * 32 + g * 8 + j;
            bb[j] = (ln < 8) ? f2bf(W_bh2[k * 8 + ln]) : (short)0;
        }
        bfr2[k0] = bb;
    }
    const float b2o = (ln < 8) ? b_bh2[ln] : 0.f;

    for (int idx = tid; idx < 64 * 39; idx += 256) {
        int rr = idx / 39, c = 161 + idx % 39;
        sx[rr][c] = 0;
    }
    {
        const int e = tid >> 2, q = tid & 3;
        const int ge = base + e;
        const bool valid = (ge < ETT);
        const int gid = valid ? te[ge] : 0;
        #pragma unroll
        for (int i = 0; i < 10; ++i) {
            float4 v = make_float4(0.f, 0.f, 0.f, 0.f);
            if (valid) v = *(const float4*)&e_final[(size_t)gid * EFW + q * 40 + i * 4];
            short4 s4; s4.x = f2bf(v.x); s4.y = f2bf(v.y); s4.z = f2bf(v.z); s4.w = f2bf(v.w);
            *(short4*)&sx[e][q * 40 + i * 4] = s4;
        }
    }
    __syncthreads();                 // stp written, staging done
    if (tid < 64) sx[tid][160] = f2bf(stp[tid]);
    __syncthreads();

    f32x4 acc[4][2];
    #pragma unroll
    for (int mf = 0; mf < 4; ++mf)
        #pragma unroll
        for (int nf = 0; nf < 2; ++nf)
            acc[mf][nf] = (f32x4){0.f, 0.f, 0.f, 0.f};
    #pragma unroll
    for (int k0 = 0; k0 < 6; ++k0) {
        short8_t a[4];
        #pragma unroll
        for (int mf = 0; mf < 4; ++mf)
            a[mf] = *(const short8_t*)&sx[mf * 16 + ln][k0 * 32 + g * 8];
        #pragma unroll
        for (int mf = 0; mf < 4; ++mf)
            #pragma unroll
            for (int nf = 0; nf < 2; ++nf)
                acc[mf][nf] = __builtin_amdgcn_mfma_f32_16x16x32_bf16(
                    a[mf], bfr[k0][nf], acc[mf][nf], 0, 0, 0);
    }
    #pragma unroll
    for (int mf = 0; mf < 4; ++mf)
        #pragma unroll
        for (int nf = 0; nf < 2; ++nf)
            #pragma unroll
            for (int r = 0; r < 4; ++r)
                sy[mf * 16 + g * 4 + r][w * 32 + nf * 16 + ln] =
                    f2bf(silu_f(acc[mf][nf][r] + (nf ? bias1 : bias0)));
    __syncthreads();

    f32x4 z = (f32x4){0.f, 0.f, 0.f, 0.f};
    #pragma unroll
    for (int k0 = 0; k0 < 4; ++k0) {
        short8_t a2 = *(const short8_t*)&sy[w * 16 + ln][k0 * 32 + g * 8];
        z = __builtin_amdgcn_mfma_f32_16x16x32_bf16(a2, bfr2[k0], z, 0, 0, 0);
    }
    #pragma unroll
    for (int r = 0; r < 4; ++r) {
        int e = base + w * 16 + g * 4 + r;
        if (ln < 8 && e < ETT) out[(size_t)e * 8 + ln] = z[r] + b2o;
    }
}

// ---------------- K6: predicted_r0 gather ----------------
__global__ void k6_r0(const float* __restrict__ r_t, const float* __restrict__ delta,
                      const int* __restrict__ tn, float* __restrict__ out)
{
    int i = blockIdx.x * 256 + threadIdx.x;
    if (i < NTT * 3) {
        int t = i / 3, d = i - t * 3;
        int n = tn[t];
        out[i] = r_t[n * 3 + d] + delta[n * 3 + d];
    }
}

extern "C" void kernel_launch(void* const* d_in, const int* in_sizes, int n_in,
                              void* d_out, int out_size, void* d_ws, size_t ws_size,
                              hipStream_t stream)
{
    const float* h_final = (const float*)d_in[0];
    const float* e_final = (const float*)d_in[1];
    const float* r_t     = (const float*)d_in[2];
    const int*   tn      = (const int*)d_in[3];
    const int*   te      = (const int*)d_in[4];
    const int*   ei      = (const int*)d_in[5];
    const float* W_nsp   = (const float*)d_in[6];
    const float* b_nsp   = (const float*)d_in[7];
    const float* W_at1   = (const float*)d_in[8];
    const float* b_at1   = (const float*)d_in[9];
    const float* W_at2   = (const float*)d_in[10];
    const float* b_at2   = (const float*)d_in[11];
    const float* W_left  = (const float*)d_in[12];
    const float* b_left  = (const float*)d_in[13];
    const float* W_right = (const float*)d_in[14];
    const float* b_right = (const float*)d_in[15];
    const float* W_el1   = (const float*)d_in[16];
    const float* b_el1   = (const float*)d_in[17];
    const float* ln_g    = (const float*)d_in[18];
    const float* ln_b    = (const float*)d_in[19];
    const float* W_el2   = (const float*)d_in[20];
    const float* b_el2   = (const float*)d_in[21];
    const float* w_tp0   = (const float*)d_in[22];
    const float* w_tp1   = (const float*)d_in[23];
    const float* W_bh1   = (const float*)d_in[24];
    const float* b_bh1   = (const float*)d_in[25];
    const float* W_bh2   = (const float*)d_in[26];
    const float* b_bh2   = (const float*)d_in[27];

    float* ws    = (float*)d_ws;
    float* Wl    = ws;                         // 16384
    float* bl    = Wl + 16384;                 // 128
    float* Wr    = bl + 128;                   // 16384
    float* br    = Wr + 16384;                 // 128   -> 33024
    float* Wc1   = ws + 33024;                 // 16384
    float* bc1   = Wc1 + 16384;                // 128   -> 49536
    short* hlb   = (short*)(ws + 49536);       // 6.4M shorts
    short* hrb   = hlb + 6400000;              // 6.4M shorts
    short* Xn    = hrb + 6400000;              // 16M shorts
    float* delta = (float*)(Xn + 16000000);    // 150000
    float* tpb   = delta + 150000;             // 100000 (unused now)
    short* Gvb   = (short*)(tpb + 100000);     // 9.6M shorts
    short* Gb    = hlb;                        // alias (reused after k3)

    float* out      = (float*)d_out;
    float* out_atom = out;                     // 10000*32
    float* out_r0   = out + 320000;            // 10000*3
    float* out_bond = out + 350000;            // 100000*8

    k0_all<<<128, 256, 0, stream>>>(W_nsp, b_nsp, W_left, b_left, W_right, b_right,
                                    W_at1, b_at1, Wl, bl, Wr, br, Wc1, bc1);
    k3pre<<<15625, 256, 0, stream>>>(e_final, Xn);
    k1_mfma<<<782, 256, 0, stream>>>(h_final, Wl, bl, Wr, br, hlb, hrb);
    k2_mfma<<<157, 256, 0, stream>>>(h_final, tn, Wc1, bc1, W_at2, b_at2, out_atom);
    hipMemsetAsync(delta, 0, 150000 * sizeof(float), stream);
    k3_edge<<<GRID3, 512, 0, stream>>>(e_final, ei, Xn, hlb, hrb, r_t, W_el1, b_el1,
                                       ln_g, ln_b, W_el2, b_el2, delta);
    k6_r0<<<(NTT * 3 + 255) / 256, 256, 0, stream>>>(r_t, delta, tn, out_r0);
    k4a_g<<<782, 256, 0, stream>>>(h_final, w_tp0, Gb);
    k4b_gv<<<2048, 256, 0, stream>>>(h_final, w_tp1, Gvb);
    k5_mfma<<<1563, 256, 0, stream>>>(e_final, te, h_final, ei, Gb, Gvb,
                                      W_bh1, b_bh1, W_bh2, b_bh2, out_bond);
}

// Round 14
// 416.368 us; speedup vs baseline: 1.2169x; 1.1137x over previous
//
#include <hip/hip_runtime.h>
#include <math.h>

#define NN   50000
#define NE   500000
#define NTT  10000
#define ETT  100000
#define HF   320      // h_final row = 128 + 3*64
#define EFW  160      // e_final row = 64 + 3*32
#define NT3  7813     // ceil(NE/64)
#define GRID3 1024

typedef __attribute__((ext_vector_type(8))) short short8_t;
typedef __attribute__((ext_vector_type(4))) float f32x4;

__device__ __forceinline__ float silu_f(float x) { return x / (1.f + __expf(-x)); }

__device__ __forceinline__ short f2bf(float f) {
    unsigned u = __float_as_uint(f);
    unsigned r = (u + 0x7fffu + ((u >> 16) & 1u)) >> 16;
    return (short)r;
}
__device__ __forceinline__ float bf2f(short s) {
    return __uint_as_float(((unsigned)(unsigned short)s) << 16);
}
// XOR swizzle helpers: return SHORT index. stride 256 shorts (512B) / 128 shorts (256B)
__device__ __forceinline__ int swz256(int row, int col) {
    return row * 256 + (((col << 1) ^ ((row & 7) << 4)) >> 1);
}
__device__ __forceinline__ int swz128(int row, int col) {
    return row * 128 + (((col << 1) ^ ((row & 7) << 4)) >> 1);
}

// ---------------- K0: fold W_nsp into W_left/W_right AND W_nsp@W_at1 ----------------
__global__ __launch_bounds__(256) void k0_all(
    const float* __restrict__ W_nsp, const float* __restrict__ b_nsp,
    const float* __restrict__ W_left, const float* __restrict__ b_left,
    const float* __restrict__ W_right, const float* __restrict__ b_right,
    const float* __restrict__ W_at1, const float* __restrict__ b_at1,
    float* __restrict__ Wl, float* __restrict__ bl,
    float* __restrict__ Wr, float* __restrict__ br,
    float* __restrict__ Wc1, float* __restrict__ bc1)
{
    if (blockIdx.x < 64) {
        int idx = blockIdx.x * 256 + threadIdx.x;
        int i = idx >> 7, j = idx & 127;
        float al = 0.f, ar = 0.f;
        for (int k = 0; k < 128; ++k) {
            float w = W_nsp[i * 128 + k];
            al = fmaf(w, W_left[k * 128 + j], al);
            ar = fmaf(w, W_right[k * 128 + j], ar);
        }
        Wl[idx] = al; Wr[idx] = ar;
        if (i == 0) {
            float cl = 0.f, cr = 0.f;
            for (int k = 0; k < 128; ++k) {
                float bn = b_nsp[k];
                cl = fmaf(bn, W_left[k * 128 + j], cl);
                cr = fmaf(bn, W_right[k * 128 + j], cr);
            }
            bl[j] = cl + b_left[j];
            br[j] = cr + b_right[j];
        }
    } else {
        int idx = (blockIdx.x - 64) * 256 + threadIdx.x;
        int i = idx >> 7, j = idx & 127;
        float a = 0.f;
        for (int k = 0; k < 128; ++k)
            a = fmaf(W_nsp[i * 128 + k], W_at1[k * 128 + j], a);
        Wc1[idx] = a;
        if (i == 0) {
            float c = 0.f;
            for (int k = 0; k < 128; ++k)
                c = fmaf(b_nsp[k], W_at1[k * 128 + j], c);
            bc1[j] = c + b_at1[j];
        }
    }
}

// ---------------- K1: hl/hr via MFMA, bf16 outputs ----------------
#define KP1 136
__global__ __launch_bounds__(256) void k1_mfma(
    const float* __restrict__ h_final,
    const float* __restrict__ Wl, const float* __restrict__ bl,
    const float* __restrict__ Wr, const float* __restrict__ br,
    short* __restrict__ hlb, short* __restrict__ hrb)
{
    __shared__ __align__(16) short sx[64][KP1];
    const int tid = threadIdx.x;
    const int w = tid >> 6, lane = tid & 63, g = lane >> 4, ln = lane & 15;

    short8_t bfr[4][4];
    float bias[4];
    #pragma unroll
    for (int nf = 0; nf < 4; ++nf) {
        int col = w * 64 + nf * 16 + ln;
        const float* Wsrc = (col < 128) ? Wl : Wr;
        int cc = col & 127;
        bias[nf] = (col < 128) ? bl[cc] : br[cc];
        #pragma unroll
        for (int k0 = 0; k0 < 4; ++k0) {
            short8_t bb;
            #pragma unroll
            for (int j = 0; j < 8; ++j)
                bb[j] = f2bf(Wsrc[(k0 * 32 + g * 8 + j) * 128 + cc]);
            bfr[k0][nf] = bb;
        }
    }

    const int base = blockIdx.x * 64;
    {
        const int e = tid >> 2, q = tid & 3;
        const int n = base + e;
        #pragma unroll
        for (int i = 0; i < 8; ++i) {
            float4 v = make_float4(0.f, 0.f, 0.f, 0.f);
            if (n < NN) v = *(const float4*)&h_final[(size_t)n * HF + q * 32 + i * 4];
            short4 s4; s4.x = f2bf(v.x); s4.y = f2bf(v.y); s4.z = f2bf(v.z); s4.w = f2bf(v.w);
            *(short4*)&sx[e][q * 32 + i * 4] = s4;
        }
    }
    __syncthreads();
    f32x4 acc[4][4];
    #pragma unroll
    for (int mf = 0; mf < 4; ++mf)
        #pragma unroll
        for (int nf = 0; nf < 4; ++nf)
            acc[mf][nf] = (f32x4){0.f, 0.f, 0.f, 0.f};
    #pragma unroll
    for (int k0 = 0; k0 < 4; ++k0) {
        short8_t a[4];
        #pragma unroll
        for (int mf = 0; mf < 4; ++mf)
            a[mf] = *(const short8_t*)&sx[mf * 16 + ln][k0 * 32 + g * 8];
        #pragma unroll
        for (int mf = 0; mf < 4; ++mf)
            #pragma unroll
            for (int nf = 0; nf < 4; ++nf)
                acc[mf][nf] = __builtin_amdgcn_mfma_f32_16x16x32_bf16(
                    a[mf], bfr[k0][nf], acc[mf][nf], 0, 0, 0);
    }
    #pragma unroll
    for (int mf = 0; mf < 4; ++mf)
        #pragma unroll
        for (int nf = 0; nf < 4; ++nf) {
            int col = w * 64 + nf * 16 + ln;
            #pragma unroll
            for (int r = 0; r < 4; ++r) {
                int n = base + mf * 16 + g * 4 + r;
                if (n < NN) {
                    short v = f2bf(acc[mf][nf][r] + bias[nf]);
                    if (col < 128) hlb[(size_t)n * 128 + col] = v;
                    else           hrb[(size_t)n * 128 + col - 128] = v;
                }
            }
        }
}

// ---------------- K2: atom head via folded MFMA (x@Wc1 -> silu -> @W_at2) ----------------
__global__ __launch_bounds__(256) void k2_mfma(
    const float* __restrict__ h_final, const int* __restrict__ tn,
    const float* __restrict__ Wc1, const float* __restrict__ bc1,
    const float* __restrict__ W_at2, const float* __restrict__ b_at2,
    float* __restrict__ out)
{
    __shared__ __align__(16) short sxf[64 * 128];
    __shared__ __align__(16) short syf[64 * 128];
    const int tid = threadIdx.x;
    const int w = tid >> 6, lane = tid & 63, g = lane >> 4, ln = lane & 15;

    short8_t bfr1[4][2];
    float biasc[2];
    #pragma unroll
    for (int nf = 0; nf < 2; ++nf) {
        int col = w * 32 + nf * 16 + ln;
        biasc[nf] = bc1[col];
        #pragma unroll
        for (int k0 = 0; k0 < 4; ++k0) {
            short8_t bb;
            #pragma unroll
            for (int j = 0; j < 8; ++j)
                bb[j] = f2bf(Wc1[(k0 * 32 + g * 8 + j) * 128 + col]);
            bfr1[k0][nf] = bb;
        }
    }
    short8_t bfr2[4][2];
    float ba2v[2];
    #pragma unroll
    for (int nf = 0; nf < 2; ++nf) {
        ba2v[nf] = b_at2[nf * 16 + ln];
        #pragma unroll
        for (int k0 = 0; k0 < 4; ++k0) {
            short8_t bb;
            #pragma unroll
            for (int j = 0; j < 8; ++j)
                bb[j] = f2bf(W_at2[(k0 * 32 + g * 8 + j) * 32 + nf * 16 + ln]);
            bfr2[k0][nf] = bb;
        }
    }

    const int base = blockIdx.x * 64;
    {
        const int e = tid >> 2, q = tid & 3;
        const int t = base + e;
        const bool valid = (t < NTT);
        const int node = valid ? tn[t] : 0;
        #pragma unroll
        for (int i = 0; i < 8; ++i) {
            float4 v = make_float4(0.f, 0.f, 0.f, 0.f);
            if (valid) v = *(const float4*)&h_final[(size_t)node * HF + q * 32 + i * 4];
            short4 s4; s4.x = f2bf(v.x); s4.y = f2bf(v.y); s4.z = f2bf(v.z); s4.w = f2bf(v.w);
            *(short4*)&sxf[swz128(e, q * 32 + i * 4)] = s4;
        }
    }
    __syncthreads();
    f32x4 acc[4][2];
    #pragma unroll
    for (int mf = 0; mf < 4; ++mf)
        #pragma unroll
        for (int nf = 0; nf < 2; ++nf)
            acc[mf][nf] = (f32x4){0.f, 0.f, 0.f, 0.f};
    #pragma unroll
    for (int k0 = 0; k0 < 4; ++k0) {
        short8_t a[4];
        #pragma unroll
        for (int mf = 0; mf < 4; ++mf)
            a[mf] = *(const short8_t*)&sxf[swz128(mf * 16 + ln, k0 * 32 + g * 8)];
        #pragma unroll
        for (int mf = 0; mf < 4; ++mf)
            #pragma unroll
            for (int nf = 0; nf < 2; ++nf)
                acc[mf][nf] = __builtin_amdgcn_mfma_f32_16x16x32_bf16(
                    a[mf], bfr1[k0][nf], acc[mf][nf], 0, 0, 0);
    }
    #pragma unroll
    for (int mf = 0; mf < 4; ++mf)
        #pragma unroll
        for (int nf = 0; nf < 2; ++nf)
            #pragma unroll
            for (int r = 0; r < 4; ++r)
                syf[swz128(mf * 16 + g * 4 + r, w * 32 + nf * 16 + ln)] =
                    f2bf(silu_f(acc[mf][nf][r] + biasc[nf]));
    __syncthreads();
    f32x4 z[2];
    z[0] = (f32x4){0.f,0.f,0.f,0.f}; z[1] = (f32x4){0.f,0.f,0.f,0.f};
    #pragma unroll
    for (int k0 = 0; k0 < 4; ++k0) {
        short8_t a2 = *(const short8_t*)&syf[swz128(w * 16 + ln, k0 * 32 + g * 8)];
        #pragma unroll
        for (int nf = 0; nf < 2; ++nf)
            z[nf] = __builtin_amdgcn_mfma_f32_16x16x32_bf16(a2, bfr2[k0][nf], z[nf], 0, 0, 0);
    }
    #pragma unroll
    for (int nf = 0; nf < 2; ++nf)
        #pragma unroll
        for (int r = 0; r < 4; ++r) {
            int t = base + w * 16 + g * 4 + r;
            if (t < NTT) out[(size_t)t * 32 + nf * 16 + ln] = z[nf][r] + ba2v[nf];
        }
}

// ---------------- K3pre: per-edge vector norms -> bf16 Xn[NE][32] ----------------
__global__ __launch_bounds__(256) void k3pre(
    const float* __restrict__ e_final, short* __restrict__ Xn)
{
    const int tid = threadIdx.x;
    const int e = blockIdx.x * 32 + (tid >> 3);
    const int sub = tid & 7;
    const float* p = &e_final[(size_t)e * EFW + 64 + sub * 12];
    float4 a = *(const float4*)p;
    float4 b = *(const float4*)(p + 4);
    float4 c = *(const float4*)(p + 8);
    short4 o;
    o.x = f2bf(sqrtf(a.x*a.x + a.y*a.y + a.z*a.z));
    o.y = f2bf(sqrtf(a.w*a.w + b.x*b.x + b.y*b.y));
    o.z = f2bf(sqrtf(b.z*b.z + b.w*b.w + c.x*c.x));
    o.w = f2bf(sqrtf(c.y*c.y + c.z*c.z + c.w*c.w));
    *(short4*)&Xn[(size_t)e * 32 + sub * 4] = o;
}

// ---------------- K3: edge MLP, 8-wave blocks, LDS-transpose LN epilogue ----------------
// Round 13 ledger: LN/dot butterflies = 1536 ds_swizzle/tile (~8.9k cyc LDS pipe)
// vs MFMA A-reads 2.7k. Fix without extra persistent regs (round-12 spill lesson):
// write y fp32 into sxf (dead after MFMA) with XOR swizzle, then row-parallel LN
// (8 thr/row, 3-stage shfl over 8-thread group). ~72 swizzles + 128 b32 writes +
// 32 b128 reads per tile. sstat/smu/spd eliminated.
__global__ __launch_bounds__(512, 4) void k3_edge(
    const float* __restrict__ e_final, const int* __restrict__ edge_index,
    const short* __restrict__ Xn,
    const short* __restrict__ hlb, const short* __restrict__ hrb,
    const float* __restrict__ r_t,
    const float* __restrict__ W_el1, const float* __restrict__ b_el1,
    const float* __restrict__ ln_g, const float* __restrict__ ln_b,
    const float* __restrict__ W_el2, const float* __restrict__ b_el2,
    float* __restrict__ delta)
{
    __shared__ __align__(16) char smem[64 * 256 * 2];   // 32 KB: sxf (bf16) / syf (fp32) union
    short* sxf = (short*)smem;          // stride 256 shorts, XOR-swizzled, K=224 used
    float* syf = (float*)smem;          // stride 128 floats, XOR-swizzled dword col
    __shared__ float slng[128], slnb[128], sw2[128];
    __shared__ float srel[64][4];
    __shared__ int   sidx[64];

    const int tid  = threadIdx.x;
    const int w    = tid >> 6;       // wave 0..7 -> cols [w*16, w*16+16)
    const int lane = tid & 63;
    const int g    = lane >> 4;
    const int ln   = lane & 15;
    const int es   = tid >> 3, qs = tid & 7;   // staging & LN: 8 threads per edge/row

    if (tid < 128) { slng[tid] = ln_g[tid]; slnb[tid] = ln_b[tid]; sw2[tid] = W_el2[tid]; }

    // B fragments of W_el1 (224x128), one 16-col slice per wave
    short8_t bfr[7];
    #pragma unroll
    for (int k0 = 0; k0 < 7; ++k0) {
        short8_t bb;
        #pragma unroll
        for (int j = 0; j < 8; ++j)
            bb[j] = f2bf(W_el1[(k0 * 32 + g * 8 + j) * 128 + w * 16 + ln]);
        bfr[k0] = bb;
    }
    const float bias0 = b_el1[w * 16 + ln];
    const float b2 = b_el2[0];

    for (int t = blockIdx.x; t < NT3; t += GRID3) {
        __syncthreads();   // previous tile's syf reads done; sxf free

        // ---- direct gather staging into swizzled sxf ----
        {
            const int ge = t * 64 + es;
            const bool valid = (ge < NE);
            int r = 0, c = 0;
            if (valid) { r = edge_index[ge]; c = edge_index[NE + ge]; }
            // e_scalar cols qs*8..+8
            #pragma unroll
            for (int i = 0; i < 2; ++i) {
                float4 v = make_float4(0.f, 0.f, 0.f, 0.f);
                if (valid) v = *(const float4*)&e_final[(size_t)ge * EFW + qs * 8 + i * 4];
                short4 s4; s4.x = f2bf(v.x); s4.y = f2bf(v.y);
                s4.z = f2bf(v.z); s4.w = f2bf(v.w);
                *(short4*)&sxf[swz256(es, qs * 8 + i * 4)] = s4;
            }
            // norms col 64+qs*4 (precomputed bf16)
            {
                short4 n0 = make_short4(0,0,0,0);
                if (valid) n0 = *(const short4*)&Xn[(size_t)ge * 32 + qs * 4];
                *(short4*)&sxf[swz256(es, 64 + qs * 4)] = n0;
            }
            // inter cols 96+qs*16..+16
            #pragma unroll
            for (int i = 0; i < 2; ++i) {
                short8_t hv, rv, pr;
                if (valid) {
                    hv = *(const short8_t*)&hlb[(size_t)r * 128 + qs * 16 + i * 8];
                    rv = *(const short8_t*)&hrb[(size_t)c * 128 + qs * 16 + i * 8];
                } else {
                    #pragma unroll
                    for (int jj = 0; jj < 8; ++jj) { hv[jj] = 0; rv[jj] = 0; }
                }
                #pragma unroll
                for (int jj = 0; jj < 8; ++jj)
                    pr[jj] = f2bf(bf2f(hv[jj]) * bf2f(rv[jj]));
                *(short8_t*)&sxf[swz256(es, 96 + qs * 16 + i * 8)] = pr;
            }
            if (qs == 0) {
                float rx = 0.f, ry = 0.f, rz = 0.f;
                if (valid) {
                    rx = r_t[r*3+0] - r_t[c*3+0];
                    ry = r_t[r*3+1] - r_t[c*3+1];
                    rz = r_t[r*3+2] - r_t[c*3+2];
                }
                sidx[es] = r;
                srel[es][0] = rx; srel[es][1] = ry; srel[es][2] = rz;
            }
        }
        __syncthreads();

        // ---- MFMA: y[64][16-slice] = x[64][224] @ W[:, w*16..+16) ----
        f32x4 acc[4];
        #pragma unroll
        for (int mf = 0; mf < 4; ++mf)
            acc[mf] = (f32x4){0.f, 0.f, 0.f, 0.f};
        #pragma unroll
        for (int k0 = 0; k0 < 7; ++k0) {
            short8_t a[4];
            #pragma unroll
            for (int mf = 0; mf < 4; ++mf)
                a[mf] = *(const short8_t*)&sxf[swz256(mf * 16 + ln, k0 * 32 + g * 8)];
            #pragma unroll
            for (int mf = 0; mf < 4; ++mf)
                acc[mf] = __builtin_amdgcn_mfma_f32_16x16x32_bf16(
                    a[mf], bfr[k0], acc[mf], 0, 0, 0);
        }
        __syncthreads();   // all A-reads done; sxf reusable as syf

        // ---- write y = acc + bias into syf (fp32, XOR-swizzled dword col) ----
        #pragma unroll
        for (int mf = 0; mf < 4; ++mf)
            #pragma unroll
            for (int r = 0; r < 4; ++r) {
                int row = mf * 16 + g * 4 + r;
                int col = (w * 16 + ln) ^ ((row & 7) << 2);
                syf[row * 128 + col] = acc[mf][r] + bias0;
            }
        __syncthreads();

        // ---- row-parallel LN + silu dot (8 threads per row) ----
        {
            float yv[16];
            float s = 0.f, q = 0.f;
            #pragma unroll
            for (int i = 0; i < 4; ++i) {
                int col4 = (qs * 16 + i * 4) ^ ((es & 7) << 2);
                float4 v = *(const float4*)&syf[es * 128 + col4];
                yv[i*4+0] = v.x; yv[i*4+1] = v.y; yv[i*4+2] = v.z; yv[i*4+3] = v.w;
                s += v.x + v.y + v.z + v.w;
                q += v.x*v.x + v.y*v.y + v.z*v.z + v.w*v.w;
            }
            s += __shfl_xor(s, 1); q += __shfl_xor(q, 1);
            s += __shfl_xor(s, 2); q += __shfl_xor(q, 2);
            s += __shfl_xor(s, 4); q += __shfl_xor(q, 4);
            const float mu = s * (1.f / 128.f);
            const float iv = rsqrtf(q * (1.f / 128.f) - mu * mu + 1e-5f);
            float p = 0.f;
            #pragma unroll
            for (int i = 0; i < 4; ++i) {
                int c0 = qs * 16 + i * 4;
                float4 gv = *(const float4*)&slng[c0];
                float4 bv = *(const float4*)&slnb[c0];
                float4 wv = *(const float4*)&sw2[c0];
                p += silu_f((yv[i*4+0] - mu) * iv * gv.x + bv.x) * wv.x;
                p += silu_f((yv[i*4+1] - mu) * iv * gv.y + bv.y) * wv.y;
                p += silu_f((yv[i*4+2] - mu) * iv * gv.z + bv.z) * wv.z;
                p += silu_f((yv[i*4+3] - mu) * iv * gv.w + bv.w) * wv.w;
            }
            p += __shfl_xor(p, 1); p += __shfl_xor(p, 2); p += __shfl_xor(p, 4);
            if (qs == 0) {
                int ge = t * 64 + es;
                if (ge < NE) {
                    float we = p + b2;
                    float rx = srel[es][0], ry = srel[es][1], rz = srel[es][2];
                    float d = sqrtf(rx*rx + ry*ry + rz*rz) + 1e-8f;
                    float f = we / (d * (d + 1.f));
                    int rr = sidx[es];
                    atomicAdd(&delta[rr*3+0], f*rx);
                    atomicAdd(&delta[rr*3+1], f*ry);
                    atomicAdd(&delta[rr*3+2], f*rz);
                }
            }
        }
    }
}

// ---------------- K4a: G = H_s @ w_tp0 (bf16 out) ----------------
__global__ __launch_bounds__(256) void k4a_g(
    const float* __restrict__ h_final, const float* __restrict__ w_tp0,
    short* __restrict__ Gb)
{
    __shared__ __align__(16) short sx[64][KP1];
    const int tid = threadIdx.x;
    const int w = tid >> 6, lane = tid & 63, g = lane >> 4, ln = lane & 15;

    short8_t bfr[4][2];
    #pragma unroll
    for (int k0 = 0; k0 < 4; ++k0)
        #pragma unroll
        for (int nf = 0; nf < 2; ++nf) {
            short8_t bb;
            #pragma unroll
            for (int j = 0; j < 8; ++j)
                bb[j] = f2bf(w_tp0[(k0 * 32 + g * 8 + j) * 128 + w * 32 + nf * 16 + ln]);
            bfr[k0][nf] = bb;
        }

    const int base = blockIdx.x * 64;
    {
        const int e = tid >> 2, q = tid & 3;
        const int n = base + e;
        #pragma unroll
        for (int i = 0; i < 8; ++i) {
            float4 v = make_float4(0.f, 0.f, 0.f, 0.f);
            if (n < NN) v = *(const float4*)&h_final[(size_t)n * HF + q * 32 + i * 4];
            short4 s4; s4.x = f2bf(v.x); s4.y = f2bf(v.y); s4.z = f2bf(v.z); s4.w = f2bf(v.w);
            *(short4*)&sx[e][q * 32 + i * 4] = s4;
        }
    }
    __syncthreads();
    f32x4 acc[4][2];
    #pragma unroll
    for (int mf = 0; mf < 4; ++mf)
        #pragma unroll
        for (int nf = 0; nf < 2; ++nf)
            acc[mf][nf] = (f32x4){0.f, 0.f, 0.f, 0.f};
    #pragma unroll
    for (int k0 = 0; k0 < 4; ++k0) {
        short8_t a[4];
        #pragma unroll
        for (int mf = 0; mf < 4; ++mf)
            a[mf] = *(const short8_t*)&sx[mf * 16 + ln][k0 * 32 + g * 8];
        #pragma unroll
        for (int mf = 0; mf < 4; ++mf)
            #pragma unroll
            for (int nf = 0; nf < 2; ++nf)
                acc[mf][nf] = __builtin_amdgcn_mfma_f32_16x16x32_bf16(
                    a[mf], bfr[k0][nf], acc[mf][nf], 0, 0, 0);
    }
    #pragma unroll
    for (int mf = 0; mf < 4; ++mf)
        #pragma unroll
        for (int nf = 0; nf < 2; ++nf) {
            int col = w * 32 + nf * 16 + ln;
            #pragma unroll
            for (int r = 0; r < 4; ++r) {
                int n = base + mf * 16 + g * 4 + r;
                if (n < NN) Gb[(size_t)n * 128 + col] = f2bf(acc[mf][nf][r]);
            }
        }
}

// ---------------- K4b: Gv[n] = w_tp1 @ V_n (bf16 out) ----------------
__global__ __launch_bounds__(256) void k4b_gv(
    const float* __restrict__ h_final, const float* __restrict__ w_tp1,
    short* __restrict__ Gvb)
{
    __shared__ float sW1T[64 * 65];
    __shared__ float sv[4][192];
    const int tid = threadIdx.x, w = tid >> 6, lane = tid & 63;
    for (int idx = tid; idx < 4096; idx += 256) {
        int i = idx >> 6, j = idx & 63;
        sW1T[j * 65 + i] = w_tp1[idx];
    }
    for (int base = blockIdx.x * 4; base < NN; base += gridDim.x * 4) {
        __syncthreads();
        if (tid < 192) {
            int nd = tid / 48, c4 = tid % 48;
            int n = base + nd;
            float4 v = make_float4(0.f, 0.f, 0.f, 0.f);
            if (n < NN) v = *(const float4*)&h_final[(size_t)n * HF + 128 + c4 * 4];
            *(float4*)&sv[nd][c4 * 4] = v;
        }
        __syncthreads();
        int n = base + w;
        if (n < NN) {
            float a0 = 0.f, a1 = 0.f, a2 = 0.f;
            for (int j = 0; j < 64; ++j) {
                float wv = sW1T[j * 65 + lane];
                a0 = fmaf(wv, sv[w][3 * j],     a0);
                a1 = fmaf(wv, sv[w][3 * j + 1], a1);
                a2 = fmaf(wv, sv[w][3 * j + 2], a2);
            }
            short* gp = &Gvb[(size_t)n * 192 + lane * 3];
            gp[0] = f2bf(a0); gp[1] = f2bf(a1); gp[2] = f2bf(a2);
        }
    }
}

// ---------------- K5: bond head, tp inline (merged k4c) + 2-stage MFMA ----------------
#define KP5 200
__global__ __launch_bounds__(256) void k5_mfma(
    const float* __restrict__ e_final, const int* __restrict__ te,
    const float* __restrict__ h_final, const int* __restrict__ edge_index,
    const short* __restrict__ Gb, const short* __restrict__ Gvb,
    const float* __restrict__ W_bh1, const float* __restrict__ b_bh1,
    const float* __restrict__ W_bh2, const float* __restrict__ b_bh2,
    float* __restrict__ out)
{
    __shared__ __align__(16) short sx[64][KP5];
    __shared__ __align__(16) short sy[64][136];
    __shared__ float stp[64];
    const int tid = threadIdx.x, w = tid >> 6, lane = tid & 63, g = lane >> 4, ln = lane & 15;
    const int base = blockIdx.x * 64;

    // ---- inline tp (was k4c): 4 threads per edge ----
    {
        const int e = tid >> 2, q = tid & 3;
        const int ge = base + e;
        const bool valid = (ge < ETT);
        const int gid = valid ? te[ge] : 0;
        const int r2 = edge_index[gid], c2 = edge_index[NE + gid];
        float s1 = 0.f, s2 = 0.f;
        #pragma unroll
        for (int i = 0; i < 4; ++i) {
            short8_t gv = *(const short8_t*)&Gb[(size_t)r2 * 128 + q * 32 + i * 8];
            float4 h0 = *(const float4*)&h_final[(size_t)c2 * HF + q * 32 + i * 8];
            float4 h1 = *(const float4*)&h_final[(size_t)c2 * HF + q * 32 + i * 8 + 4];
            s1 += bf2f(gv[0])*h0.x + bf2f(gv[1])*h0.y + bf2f(gv[2])*h0.z + bf2f(gv[3])*h0.w
                + bf2f(gv[4])*h1.x + bf2f(gv[5])*h1.y + bf2f(gv[6])*h1.z + bf2f(gv[7])*h1.w;
        }
        #pragma unroll
        for (int i = 0; i < 6; ++i) {
            short8_t gv = *(const short8_t*)&Gvb[(size_t)c2 * 192 + q * 48 + i * 8];
            float4 h0 = *(const float4*)&h_final[(size_t)r2 * HF + 128 + q * 48 + i * 8];
            float4 h1 = *(const float4*)&h_final[(size_t)r2 * HF + 128 + q * 48 + i * 8 + 4];
            s2 += bf2f(gv[0])*h0.x + bf2f(gv[1])*h0.y + bf2f(gv[2])*h0.z + bf2f(gv[3])*h0.w
                + bf2f(gv[4])*h1.x + bf2f(gv[5])*h1.y + bf2f(gv[6])*h1.z + bf2f(gv[7])*h1.w;
        }
        float res = s1 * (1.f / 128.f) + s2 * (1.f / 110.85125168440814f);
        res += __shfl_xor(res, 1); res += __shfl_xor(res, 2);
        if (q == 0) stp[e] = res;
    }

    short8_t bfr[6][2];
    #pragma unroll
    for (int k0 = 0; k0 < 6; ++k0)
        #pragma unroll
        for (int nf = 0; nf < 2; ++nf) {
            short8_t bb;
            #pragma unroll
            for (int j = 0; j < 8; ++j) {
                int k = k0 * 32 + g * 8 + j;
                float v = 0.f;
                if (k < 160)       v = W_bh1[(size_t)(k + 1) * 128 + w * 32 + nf * 16 + ln];
                else if (k == 160) v = W_bh1[w * 32 + nf * 16 + ln];
                bb[j] = f2bf(v);
            }
            bfr[k0][nf] = bb;
        }
    const float bias0 = b_bh1[w * 32 + ln];
    const float bias1 = b_bh1[w * 32 + 16 + ln];

    short8_t bfr2[4];
    #pragma unroll
    for (int k0 = 0; k0 < 4; ++k0) {
        short8_t bb;
        #pragma unroll
        for (int j = 0; j < 8; ++j) {
            int k = k0 * 32 + g * 8 + j;
            bb[j] = (ln < 8) ? f2bf(W_bh2[k * 8 + ln]) : (short)0;
        }
        bfr2[k0] = bb;
    }
    const float b2o = (ln < 8) ? b_bh2[ln] : 0.f;

    for (int idx = tid; idx < 64 * 39; idx += 256) {
        int rr = idx / 39, c = 161 + idx % 39;
        sx[rr][c] = 0;
    }
    {
        const int e = tid >> 2, q = tid & 3;
        const int ge = base + e;
        const bool valid = (ge < ETT);
        const int gid = valid ? te[ge] : 0;
        #pragma unroll
        for (int i = 0; i < 10; ++i) {
            float4 v = make_float4(0.f, 0.f, 0.f, 0.f);
            if (valid) v = *(const float4*)&e_final[(size_t)gid * EFW + q * 40 + i * 4];
            short4 s4; s4.x = f2bf(v.x); s4.y = f2bf(v.y); s4.z = f2bf(v.z); s4.w = f2bf(v.w);
            *(short4*)&sx[e][q * 40 + i * 4] = s4;
        }
    }
    __syncthreads();                 // stp written, staging done
    if (tid < 64) sx[tid][160] = f2bf(stp[tid]);
    __syncthreads();

    f32x4 acc[4][2];
    #pragma unroll
    for (int mf = 0; mf < 4; ++mf)
        #pragma unroll
        for (int nf = 0; nf < 2; ++nf)
            acc[mf][nf] = (f32x4){0.f, 0.f, 0.f, 0.f};
    #pragma unroll
    for (int k0 = 0; k0 < 6; ++k0) {
        short8_t a[4];
        #pragma unroll
        for (int mf = 0; mf < 4; ++mf)
            a[mf] = *(const short8_t*)&sx[mf * 16 + ln][k0 * 32 + g * 8];
        #pragma unroll
        for (int mf = 0; mf < 4; ++mf)
            #pragma unroll
            for (int nf = 0; nf < 2; ++nf)
                acc[mf][nf] = __builtin_amdgcn_mfma_f32_16x16x32_bf16(
                    a[mf], bfr[k0][nf], acc[mf][nf], 0, 0, 0);
    }
    #pragma unroll
    for (int mf = 0; mf < 4; ++mf)
        #pragma unroll
        for (int nf = 0; nf < 2; ++nf)
            #pragma unroll
            for (int r = 0; r < 4; ++r)
                sy[mf * 16 + g * 4 + r][w * 32 + nf * 16 + ln] =
                    f2bf(silu_f(acc[mf][nf][r] + (nf ? bias1 : bias0)));
    __syncthreads();

    f32x4 z = (f32x4){0.f, 0.f, 0.f, 0.f};
    #pragma unroll
    for (int k0 = 0; k0 < 4; ++k0) {
        short8_t a2 = *(const short8_t*)&sy[w * 16 + ln][k0 * 32 + g * 8];
        z = __builtin_amdgcn_mfma_f32_16x16x32_bf16(a2, bfr2[k0], z, 0, 0, 0);
    }
    #pragma unroll
    for (int r = 0; r < 4; ++r) {
        int e = base + w * 16 + g * 4 + r;
        if (ln < 8 && e < ETT) out[(size_t)e * 8 + ln] = z[r] + b2o;
    }
}

// ---------------- K6: predicted_r0 gather ----------------
__global__ void k6_r0(const float* __restrict__ r_t, const float* __restrict__ delta,
                      const int* __restrict__ tn, float* __restrict__ out)
{
    int i = blockIdx.x * 256 + threadIdx.x;
    if (i < NTT * 3) {
        int t = i / 3, d = i - t * 3;
        int n = tn[t];
        out[i] = r_t[n * 3 + d] + delta[n * 3 + d];
    }
}

extern "C" void kernel_launch(void* const* d_in, const int* in_sizes, int n_in,
                              void* d_out, int out_size, void* d_ws, size_t ws_size,
                              hipStream_t stream)
{
    const float* h_final = (const float*)d_in[0];
    const float* e_final = (const float*)d_in[1];
    const float* r_t     = (const float*)d_in[2];
    const int*   tn      = (const int*)d_in[3];
    const int*   te      = (const int*)d_in[4];
    const int*   ei      = (const int*)d_in[5];
    const float* W_nsp   = (const float*)d_in[6];
    const float* b_nsp   = (const float*)d_in[7];
    const float* W_at1   = (const float*)d_in[8];
    const float* b_at1   = (const float*)d_in[9];
    const float* W_at2   = (const float*)d_in[10];
    const float* b_at2   = (const float*)d_in[11];
    const float* W_left  = (const float*)d_in[12];
    const float* b_left  = (const float*)d_in[13];
    const float* W_right = (const float*)d_in[14];
    const float* b_right = (const float*)d_in[15];
    const float* W_el1   = (const float*)d_in[16];
    const float* b_el1   = (const float*)d_in[17];
    const float* ln_g    = (const float*)d_in[18];
    const float* ln_b    = (const float*)d_in[19];
    const float* W_el2   = (const float*)d_in[20];
    const float* b_el2   = (const float*)d_in[21];
    const float* w_tp0   = (const float*)d_in[22];
    const float* w_tp1   = (const float*)d_in[23];
    const float* W_bh1   = (const float*)d_in[24];
    const float* b_bh1   = (const float*)d_in[25];
    const float* W_bh2   = (const float*)d_in[26];
    const float* b_bh2   = (const float*)d_in[27];

    float* ws    = (float*)d_ws;
    float* Wl    = ws;                         // 16384
    float* bl    = Wl + 16384;                 // 128
    float* Wr    = bl + 128;                   // 16384
    float* br    = Wr + 16384;                 // 128   -> 33024
    float* Wc1   = ws + 33024;                 // 16384
    float* bc1   = Wc1 + 16384;                // 128   -> 49536
    short* hlb   = (short*)(ws + 49536);       // 6.4M shorts
    short* hrb   = hlb + 6400000;              // 6.4M shorts
    short* Xn    = hrb + 6400000;              // 16M shorts
    float* delta = (float*)(Xn + 16000000);    // 150000
    float* tpb   = delta + 150000;             // 100000 (unused now)
    short* Gvb   = (short*)(tpb + 100000);     // 9.6M shorts
    short* Gb    = hlb;                        // alias (reused after k3)

    float* out      = (float*)d_out;
    float* out_atom = out;                     // 10000*32
    float* out_r0   = out + 320000;            // 10000*3
    float* out_bond = out + 350000;            // 100000*8

    k0_all<<<128, 256, 0, stream>>>(W_nsp, b_nsp, W_left, b_left, W_right, b_right,
                                    W_at1, b_at1, Wl, bl, Wr, br, Wc1, bc1);
    k3pre<<<15625, 256, 0, stream>>>(e_final, Xn);
    k1_mfma<<<782, 256, 0, stream>>>(h_final, Wl, bl, Wr, br, hlb, hrb);
    k2_mfma<<<157, 256, 0, stream>>>(h_final, tn, Wc1, bc1, W_at2, b_at2, out_atom);
    hipMemsetAsync(delta, 0, 150000 * sizeof(float), stream);
    k3_edge<<<GRID3, 512, 0, stream>>>(e_final, ei, Xn, hlb, hrb, r_t, W_el1, b_el1,
                                       ln_g, ln_b, W_el2, b_el2, delta);
    k6_r0<<<(NTT * 3 + 255) / 256, 256, 0, stream>>>(r_t, delta, tn, out_r0);
    k4a_g<<<782, 256, 0, stream>>>(h_final, w_tp0, Gb);
    k4b_gv<<<2048, 256, 0, stream>>>(h_final, w_tp1, Gvb);
    k5_mfma<<<1563, 256, 0, stream>>>(e_final, te, h_final, ei, Gb, Gvb,
                                      W_bh1, b_bh1, W_bh2, b_bh2, out_bond);
}